// Round 1
// baseline (5820.924 us; speedup 1.0000x reference)
//
#include <hip/hip_runtime.h>

#define NF 128   // FEATURE == HIDDEN
#define NC 64    // CLASSES

// ---------------- small transpose: Wt[k*J + j] = W[j*K + k] ----------------
__global__ void transpose_kernel(const float* __restrict__ W, float* __restrict__ Wt,
                                 int J, int K) {
  int idx = blockIdx.x * blockDim.x + threadIdx.x;
  if (idx >= J * K) return;
  int j = idx / K, k = idx % K;
  Wt[k * J + j] = W[j * K + k];
}

// ---------------- edge scatter-add: agg[dst] += feat[src]; cnt[dst] += 1 ----
// 32 threads per edge, each handles one float4 (4 features).
__global__ void scatter_kernel(const float* __restrict__ feat, const int* __restrict__ src,
                               const int* __restrict__ dst, float* __restrict__ agg,
                               float* __restrict__ cnt, int nE, int do_cnt) {
  long long tid = (long long)blockIdx.x * blockDim.x + threadIdx.x;
  int e = (int)(tid >> 5);
  if (e >= nE) return;
  int q = (int)(tid & 31);
  int s = src[e], d = dst[e];
  const float4 v = ((const float4*)(feat + (size_t)s * NF))[q];
  float* o = agg + (size_t)d * NF + q * 4;
  atomicAdd(o + 0, v.x);
  atomicAdd(o + 1, v.y);
  atomicAdd(o + 2, v.z);
  atomicAdd(o + 3, v.w);
  if (do_cnt && q == 0) atomicAdd(cnt + d, 1.0f);
}

// ---------------- layer 1: h = relu(mean@W1l^T + b1l + x@W1r^T) -------------
// block = 256 threads, 16 nodes per block; thread j computes output feature j
// for 8 nodes (y = upper/lower half). Weights pre-transposed: Wt[k*128 + j].
__global__ __launch_bounds__(256) void layer1_kernel(
    const float* __restrict__ x, const float* __restrict__ agg,
    const float* __restrict__ cnt, const float* __restrict__ W1lt,
    const float* __restrict__ b1l, const float* __restrict__ W1rt,
    float* __restrict__ h, int nN) {
  const int t = threadIdx.x;
  const int j = t & 127;
  const int y = t >> 7;  // 0..1
  const int base = blockIdx.x * 16;
  __shared__ float ms[16][NF];
  __shared__ float xs[16][NF];
  for (int i = t; i < 16 * 32; i += 256) {
    int m = i >> 5, q = i & 31;
    int n = base + m;
    if (n < nN) {
      float inv = 1.0f / fmaxf(cnt[n], 1.0f);
      float4 av = ((const float4*)(agg + (size_t)n * NF))[q];
      float4 xv = ((const float4*)(x + (size_t)n * NF))[q];
      av.x *= inv; av.y *= inv; av.z *= inv; av.w *= inv;
      ((float4*)ms[m])[q] = av;
      ((float4*)xs[m])[q] = xv;
    }
  }
  __syncthreads();

  float acc[8];
  const float bj = b1l[j];
#pragma unroll
  for (int m = 0; m < 8; ++m) acc[m] = bj;

  const float* wl = W1lt + j;  // wl[k*128] = W1l[j][k]
  const float* wr = W1rt + j;
  for (int k4 = 0; k4 < 32; ++k4) {
    const int k = k4 * 4;
    float a0 = wl[(k + 0) * NF];
    float a1 = wl[(k + 1) * NF];
    float a2 = wl[(k + 2) * NF];
    float a3 = wl[(k + 3) * NF];
    float b0 = wr[(k + 0) * NF];
    float b1 = wr[(k + 1) * NF];
    float b2 = wr[(k + 2) * NF];
    float b3 = wr[(k + 3) * NF];
#pragma unroll
    for (int m = 0; m < 8; ++m) {
      const int mm = y * 8 + m;
      float4 m4 = ((const float4*)ms[mm])[k4];
      float4 x4 = ((const float4*)xs[mm])[k4];
      acc[m] += a0 * m4.x + a1 * m4.y + a2 * m4.z + a3 * m4.w
              + b0 * x4.x + b1 * x4.y + b2 * x4.z + b3 * x4.w;
    }
  }
#pragma unroll
  for (int m = 0; m < 8; ++m) {
    int n = base + y * 8 + m;
    if (n < nN) h[(size_t)n * NF + j] = fmaxf(acc[m], 0.0f);
  }
}

// ---------------- layer 2 + log_softmax ------------------------------------
// block = 256 threads = 4 waves; each wave (64 lanes == 64 classes) handles
// 4 nodes; log-softmax via 64-lane shuffle reductions.
__global__ __launch_bounds__(256) void layer2_kernel(
    const float* __restrict__ hbuf, const float* __restrict__ agg,
    const float* __restrict__ cnt, const float* __restrict__ W2lt,
    const float* __restrict__ b2l, const float* __restrict__ W2rt,
    float* __restrict__ out, int nN) {
  const int t = threadIdx.x;
  const int c = t & 63;
  const int y = t >> 6;  // 0..3
  const int base = blockIdx.x * 16;
  __shared__ float ms[16][NF];
  __shared__ float hs[16][NF];
  for (int i = t; i < 16 * 32; i += 256) {
    int m = i >> 5, q = i & 31;
    int n = base + m;
    if (n < nN) {
      float inv = 1.0f / fmaxf(cnt[n], 1.0f);
      float4 av = ((const float4*)(agg + (size_t)n * NF))[q];
      float4 hv = ((const float4*)(hbuf + (size_t)n * NF))[q];
      av.x *= inv; av.y *= inv; av.z *= inv; av.w *= inv;
      ((float4*)ms[m])[q] = av;
      ((float4*)hs[m])[q] = hv;
    }
  }
  __syncthreads();

  float acc[4];
  const float bc = b2l[c];
#pragma unroll
  for (int m = 0; m < 4; ++m) acc[m] = bc;

  const float* wl = W2lt + c;  // wl[k*64] = W2l[c][k]
  const float* wr = W2rt + c;
  for (int k4 = 0; k4 < 32; ++k4) {
    const int k = k4 * 4;
    float a0 = wl[(k + 0) * NC];
    float a1 = wl[(k + 1) * NC];
    float a2 = wl[(k + 2) * NC];
    float a3 = wl[(k + 3) * NC];
    float b0 = wr[(k + 0) * NC];
    float b1 = wr[(k + 1) * NC];
    float b2 = wr[(k + 2) * NC];
    float b3 = wr[(k + 3) * NC];
#pragma unroll
    for (int m = 0; m < 4; ++m) {
      const int mm = y * 4 + m;
      float4 m4 = ((const float4*)ms[mm])[k4];
      float4 h4 = ((const float4*)hs[mm])[k4];
      acc[m] += a0 * m4.x + a1 * m4.y + a2 * m4.z + a3 * m4.w
              + b0 * h4.x + b1 * h4.y + b2 * h4.z + b3 * h4.w;
    }
  }

#pragma unroll
  for (int m = 0; m < 4; ++m) {
    int n = base + y * 4 + m;
    float v = acc[m];
    float mx = v;
#pragma unroll
    for (int off = 32; off > 0; off >>= 1) mx = fmaxf(mx, __shfl_xor(mx, off));
    float ex = expf(v - mx);
    float sm = ex;
#pragma unroll
    for (int off = 32; off > 0; off >>= 1) sm += __shfl_xor(sm, off);
    if (n < nN) out[(size_t)n * NC + c] = v - mx - logf(sm);
  }
}

extern "C" void kernel_launch(void* const* d_in, const int* in_sizes, int n_in,
                              void* d_out, int out_size, void* d_ws, size_t ws_size,
                              hipStream_t stream) {
  const float* x   = (const float*)d_in[0];
  const int*   ei  = (const int*)d_in[1];
  const float* W1l = (const float*)d_in[2];
  const float* b1l = (const float*)d_in[3];
  const float* W1r = (const float*)d_in[4];
  const float* W2l = (const float*)d_in[5];
  const float* b2l = (const float*)d_in[6];
  const float* W2r = (const float*)d_in[7];
  float* out = (float*)d_out;

  const int nN = in_sizes[0] / NF;  // 100000
  const int nE = in_sizes[1] / 2;   // 1600000
  const int* src = ei;
  const int* dst = ei + nE;

  float* ws   = (float*)d_ws;
  float* agg  = ws;                          // nN*NF
  float* hbuf = agg + (size_t)nN * NF;       // nN*NF
  float* cnt  = hbuf + (size_t)nN * NF;      // nN
  float* W1lt = cnt + nN;                    // NF*NF
  float* W1rt = W1lt + NF * NF;              // NF*NF
  float* W2lt = W1rt + NF * NF;              // NF*NC
  float* W2rt = W2lt + NC * NF;              // NF*NC

  hipMemsetAsync(agg, 0, (size_t)nN * NF * sizeof(float), stream);
  hipMemsetAsync(cnt, 0, (size_t)nN * sizeof(float), stream);

  transpose_kernel<<<(NF * NF + 255) / 256, 256, 0, stream>>>(W1l, W1lt, NF, NF);
  transpose_kernel<<<(NF * NF + 255) / 256, 256, 0, stream>>>(W1r, W1rt, NF, NF);
  transpose_kernel<<<(NC * NF + 255) / 256, 256, 0, stream>>>(W2l, W2lt, NC, NF);
  transpose_kernel<<<(NC * NF + 255) / 256, 256, 0, stream>>>(W2r, W2rt, NC, NF);

  {
    long long threads = (long long)nE * 32;
    int blocks = (int)((threads + 255) / 256);
    scatter_kernel<<<blocks, 256, 0, stream>>>(x, src, dst, agg, cnt, nE, 1);
  }
  {
    int blocks = (nN + 15) / 16;
    layer1_kernel<<<blocks, 256, 0, stream>>>(x, agg, cnt, W1lt, b1l, W1rt, hbuf, nN);
  }

  hipMemsetAsync(agg, 0, (size_t)nN * NF * sizeof(float), stream);

  {
    long long threads = (long long)nE * 32;
    int blocks = (int)((threads + 255) / 256);
    scatter_kernel<<<blocks, 256, 0, stream>>>(hbuf, src, dst, agg, nullptr, nE, 0);
  }
  {
    int blocks = (nN + 15) / 16;
    layer2_kernel<<<blocks, 256, 0, stream>>>(hbuf, agg, cnt, W2lt, b2l, W2rt, out, nN);
  }
}

// Round 2
// 799.434 us; speedup vs baseline: 7.2813x; 7.2813x over previous
//
#include <hip/hip_runtime.h>

#define NF 128   // FEATURE == HIDDEN
#define NC 64    // CLASSES

// ---------------- small transpose: Wt[k*J + j] = W[j*K + k] ----------------
__global__ void transpose_kernel(const float* __restrict__ W, float* __restrict__ Wt,
                                 int J, int K) {
  int idx = blockIdx.x * blockDim.x + threadIdx.x;
  if (idx >= J * K) return;
  int j = idx / K, k = idx % K;
  Wt[k * J + j] = W[j * K + k];
}

// ---------------- CSR build: histogram of dst -------------------------------
__global__ void hist_kernel(const int* __restrict__ dst, int* __restrict__ deg, int nE) {
  int e = blockIdx.x * blockDim.x + threadIdx.x;
  if (e < nE) atomicAdd(&deg[dst[e]], 1);
}

// scan phase 1: per-block (1024 elems) exclusive scan of deg -> off, block sums
__global__ __launch_bounds__(256) void scan1_kernel(const int* __restrict__ deg,
                                                    int* __restrict__ off,
                                                    int* __restrict__ bsum, int nN) {
  const int t = threadIdx.x;
  const int base = blockIdx.x * 1024 + t * 4;
  int v[4];
  int tsum = 0;
#pragma unroll
  for (int k = 0; k < 4; ++k) {
    v[k] = (base + k < nN) ? deg[base + k] : 0;
    tsum += v[k];
  }
  // wave inclusive scan of tsum
  int lane = t & 63, wid = t >> 6;
  int x = tsum;
#pragma unroll
  for (int d = 1; d < 64; d <<= 1) {
    int y = __shfl_up(x, d);
    if (lane >= d) x += y;
  }
  __shared__ int wsum[4];
  if (lane == 63) wsum[wid] = x;
  __syncthreads();
  int wbase = 0;
  for (int w = 0; w < wid; ++w) wbase += wsum[w];
  int run = wbase + x - tsum;  // exclusive prefix for this thread
#pragma unroll
  for (int k = 0; k < 4; ++k) {
    if (base + k < nN) off[base + k] = run;
    run += v[k];
  }
  if (t == 0) bsum[blockIdx.x] = wsum[0] + wsum[1] + wsum[2] + wsum[3];
}

// scan phase 2: serial exclusive scan of block sums (~98 entries)
__global__ void scan2_kernel(int* __restrict__ bsum, int nb) {
  if (threadIdx.x == 0 && blockIdx.x == 0) {
    int run = 0;
    for (int i = 0; i < nb; ++i) { int t = bsum[i]; bsum[i] = run; run += t; }
  }
}

// scan phase 3: add block offsets; copy to cursor for the permute pass
__global__ void scan3_kernel(int* __restrict__ off, int* __restrict__ cursor,
                             const int* __restrict__ bsum, int nN) {
  int i = blockIdx.x * blockDim.x + threadIdx.x;
  if (i < nN) {
    int v = off[i] + bsum[i >> 10];
    off[i] = v;
    cursor[i] = v;
  }
}

// permute: esrc sorted by dst
__global__ void permute_kernel(const int* __restrict__ src, const int* __restrict__ dst,
                               int* __restrict__ cursor, int* __restrict__ esrc, int nE) {
  int e = blockIdx.x * blockDim.x + threadIdx.x;
  if (e < nE) {
    int p = atomicAdd(&cursor[dst[e]], 1);
    esrc[p] = src[e];
  }
}

// ---------------- gather-aggregate: mean of src rows per node ---------------
// one 64-lane wave per node; lane q accumulates features [2q, 2q+1].
__global__ __launch_bounds__(256) void gather_mean_kernel(
    const float* __restrict__ feat, const int* __restrict__ esrc,
    const int* __restrict__ off, const int* __restrict__ deg,
    float* __restrict__ aggm, int nN) {
  const int w = (blockIdx.x * blockDim.x + threadIdx.x) >> 6;
  const int lane = threadIdx.x & 63;
  if (w >= nN) return;
  const int o = off[w];
  const int d = deg[w];
  const float2* f2 = (const float2*)feat;
  float ax = 0.0f, ay = 0.0f;
  int sn = (d > 0) ? esrc[o] : 0;
  for (int i = 0; i < d;) {
    int s = sn;
    ++i;
    if (i < d) sn = esrc[o + i];  // prefetch next index while gather in flight
    float2 v = f2[(size_t)s * 64 + lane];
    ax += v.x; ay += v.y;
  }
  float inv = 1.0f / fmaxf((float)d, 1.0f);
  ((float2*)aggm)[(size_t)w * 64 + lane] = make_float2(ax * inv, ay * inv);
}

// ---------------- layer 1: h = relu(mean@W1l^T + b1l + x@W1r^T) -------------
__global__ __launch_bounds__(256) void layer1_kernel(
    const float* __restrict__ x, const float* __restrict__ aggm,
    const float* __restrict__ W1lt, const float* __restrict__ b1l,
    const float* __restrict__ W1rt, float* __restrict__ h, int nN) {
  const int t = threadIdx.x;
  const int j = t & 127;
  const int y = t >> 7;  // 0..1
  const int base = blockIdx.x * 16;
  __shared__ float ms[16][NF];
  __shared__ float xs[16][NF];
  for (int i = t; i < 16 * 32; i += 256) {
    int m = i >> 5, q = i & 31;
    int n = base + m;
    if (n < nN) {
      ((float4*)ms[m])[q] = ((const float4*)(aggm + (size_t)n * NF))[q];
      ((float4*)xs[m])[q] = ((const float4*)(x + (size_t)n * NF))[q];
    }
  }
  __syncthreads();

  float acc[8];
  const float bj = b1l[j];
#pragma unroll
  for (int m = 0; m < 8; ++m) acc[m] = bj;

  const float* wl = W1lt + j;
  const float* wr = W1rt + j;
  for (int k4 = 0; k4 < 32; ++k4) {
    const int k = k4 * 4;
    float a0 = wl[(k + 0) * NF];
    float a1 = wl[(k + 1) * NF];
    float a2 = wl[(k + 2) * NF];
    float a3 = wl[(k + 3) * NF];
    float b0 = wr[(k + 0) * NF];
    float b1 = wr[(k + 1) * NF];
    float b2 = wr[(k + 2) * NF];
    float b3 = wr[(k + 3) * NF];
#pragma unroll
    for (int m = 0; m < 8; ++m) {
      const int mm = y * 8 + m;
      float4 m4 = ((const float4*)ms[mm])[k4];
      float4 x4 = ((const float4*)xs[mm])[k4];
      acc[m] += a0 * m4.x + a1 * m4.y + a2 * m4.z + a3 * m4.w
              + b0 * x4.x + b1 * x4.y + b2 * x4.z + b3 * x4.w;
    }
  }
#pragma unroll
  for (int m = 0; m < 8; ++m) {
    int n = base + y * 8 + m;
    if (n < nN) h[(size_t)n * NF + j] = fmaxf(acc[m], 0.0f);
  }
}

// ---------------- layer 2 + log_softmax ------------------------------------
__global__ __launch_bounds__(256) void layer2_kernel(
    const float* __restrict__ hbuf, const float* __restrict__ aggm,
    const float* __restrict__ W2lt, const float* __restrict__ b2l,
    const float* __restrict__ W2rt, float* __restrict__ out, int nN) {
  const int t = threadIdx.x;
  const int c = t & 63;
  const int y = t >> 6;  // 0..3
  const int base = blockIdx.x * 16;
  __shared__ float ms[16][NF];
  __shared__ float hs[16][NF];
  for (int i = t; i < 16 * 32; i += 256) {
    int m = i >> 5, q = i & 31;
    int n = base + m;
    if (n < nN) {
      ((float4*)ms[m])[q] = ((const float4*)(aggm + (size_t)n * NF))[q];
      ((float4*)hs[m])[q] = ((const float4*)(hbuf + (size_t)n * NF))[q];
    }
  }
  __syncthreads();

  float acc[4];
  const float bc = b2l[c];
#pragma unroll
  for (int m = 0; m < 4; ++m) acc[m] = bc;

  const float* wl = W2lt + c;
  const float* wr = W2rt + c;
  for (int k4 = 0; k4 < 32; ++k4) {
    const int k = k4 * 4;
    float a0 = wl[(k + 0) * NC];
    float a1 = wl[(k + 1) * NC];
    float a2 = wl[(k + 2) * NC];
    float a3 = wl[(k + 3) * NC];
    float b0 = wr[(k + 0) * NC];
    float b1 = wr[(k + 1) * NC];
    float b2 = wr[(k + 2) * NC];
    float b3 = wr[(k + 3) * NC];
#pragma unroll
    for (int m = 0; m < 4; ++m) {
      const int mm = y * 4 + m;
      float4 m4 = ((const float4*)ms[mm])[k4];
      float4 h4 = ((const float4*)hs[mm])[k4];
      acc[m] += a0 * m4.x + a1 * m4.y + a2 * m4.z + a3 * m4.w
              + b0 * h4.x + b1 * h4.y + b2 * h4.z + b3 * h4.w;
    }
  }

#pragma unroll
  for (int m = 0; m < 4; ++m) {
    int n = base + y * 4 + m;
    float v = acc[m];
    float mx = v;
#pragma unroll
    for (int off2 = 32; off2 > 0; off2 >>= 1) mx = fmaxf(mx, __shfl_xor(mx, off2));
    float ex = expf(v - mx);
    float sm = ex;
#pragma unroll
    for (int off2 = 32; off2 > 0; off2 >>= 1) sm += __shfl_xor(sm, off2);
    if (n < nN) out[(size_t)n * NC + c] = v - mx - logf(sm);
  }
}

extern "C" void kernel_launch(void* const* d_in, const int* in_sizes, int n_in,
                              void* d_out, int out_size, void* d_ws, size_t ws_size,
                              hipStream_t stream) {
  const float* x   = (const float*)d_in[0];
  const int*   ei  = (const int*)d_in[1];
  const float* W1l = (const float*)d_in[2];
  const float* b1l = (const float*)d_in[3];
  const float* W1r = (const float*)d_in[4];
  const float* W2l = (const float*)d_in[5];
  const float* b2l = (const float*)d_in[6];
  const float* W2r = (const float*)d_in[7];
  float* out = (float*)d_out;

  const int nN = in_sizes[0] / NF;  // 100000
  const int nE = in_sizes[1] / 2;   // 1600000
  const int* src = ei;
  const int* dst = ei + nE;

  float* ws   = (float*)d_ws;
  float* agg  = ws;                          // nN*NF
  float* hbuf = agg + (size_t)nN * NF;       // nN*NF
  float* W1lt = hbuf + (size_t)nN * NF;      // NF*NF
  float* W1rt = W1lt + NF * NF;              // NF*NF
  float* W2lt = W1rt + NF * NF;              // NF*NC
  float* W2rt = W2lt + NC * NF;              // NF*NC
  int*   deg  = (int*)(W2rt + NC * NF);      // nN
  int*   off  = deg + nN;                    // nN
  int*   cur  = off + nN;                    // nN
  int*   bsum = cur + nN;                    // 128
  int*   esrc = bsum + 128;                  // nE

  const int nb1024 = (nN + 1023) / 1024;

  hipMemsetAsync(deg, 0, (size_t)nN * sizeof(int), stream);

  transpose_kernel<<<(NF * NF + 255) / 256, 256, 0, stream>>>(W1l, W1lt, NF, NF);
  transpose_kernel<<<(NF * NF + 255) / 256, 256, 0, stream>>>(W1r, W1rt, NF, NF);
  transpose_kernel<<<(NC * NF + 255) / 256, 256, 0, stream>>>(W2l, W2lt, NC, NF);
  transpose_kernel<<<(NC * NF + 255) / 256, 256, 0, stream>>>(W2r, W2rt, NC, NF);

  // --- build CSR by destination ---
  hist_kernel<<<(nE + 255) / 256, 256, 0, stream>>>(dst, deg, nE);
  scan1_kernel<<<nb1024, 256, 0, stream>>>(deg, off, bsum, nN);
  scan2_kernel<<<1, 64, 0, stream>>>(bsum, nb1024);
  scan3_kernel<<<(nN + 255) / 256, 256, 0, stream>>>(off, cur, bsum, nN);
  permute_kernel<<<(nE + 255) / 256, 256, 0, stream>>>(src, dst, cur, esrc, nE);

  // --- layer 1 ---
  gather_mean_kernel<<<(nN + 3) / 4, 256, 0, stream>>>(x, esrc, off, deg, agg, nN);
  layer1_kernel<<<(nN + 15) / 16, 256, 0, stream>>>(x, agg, W1lt, b1l, W1rt, hbuf, nN);

  // --- layer 2 ---
  gather_mean_kernel<<<(nN + 3) / 4, 256, 0, stream>>>(hbuf, esrc, off, deg, agg, nN);
  layer2_kernel<<<(nN + 15) / 16, 256, 0, stream>>>(hbuf, agg, W2lt, b2l, W2rt, out, nN);
}

// Round 3
// 550.811 us; speedup vs baseline: 10.5679x; 1.4514x over previous
//
#include <hip/hip_runtime.h>

#define NF 128   // FEATURE == HIDDEN
#define NC 64    // CLASSES

typedef short short8 __attribute__((ext_vector_type(8)));
typedef unsigned short ushort;
typedef float f32x4 __attribute__((ext_vector_type(4)));

__device__ __forceinline__ ushort f2b(float x) {  // RNE float->bf16
  unsigned u = __builtin_bit_cast(unsigned, x);
  u += 0x7fffu + ((u >> 16) & 1u);
  return (ushort)(u >> 16);
}
__device__ __forceinline__ float b2f_lo(unsigned v) {
  return __builtin_bit_cast(float, v << 16);
}
__device__ __forceinline__ float b2f_hi(unsigned v) {
  return __builtin_bit_cast(float, v & 0xffff0000u);
}

// ---------------- cast x (fp32) -> bf16 -------------------------------------
__global__ void cast_kernel(const float* __restrict__ x, ushort* __restrict__ xb, int n4) {
  int i = blockIdx.x * blockDim.x + threadIdx.x;
  if (i >= n4) return;
  float4 v = ((const float4*)x)[i];
  ushort4 o;
  o.x = f2b(v.x); o.y = f2b(v.y); o.z = f2b(v.z); o.w = f2b(v.w);
  ((ushort4*)xb)[i] = o;
}

// ---------------- weight pack: Wcat[k][n] -> MFMA B-fragment order ----------
// packed[((kt*NT + nt)*64 + lane)*8 + j] = Wcat[kt*32 + (lane>>4)*8 + j][nt*16 + (lane&15)]
// Wcat[k][n] = Wl[n][k] (k<128) else Wr[n][k-128]
__global__ void pack_kernel(const float* __restrict__ Wl, const float* __restrict__ Wr,
                            ushort* __restrict__ Wp, int N) {
  int tid = blockIdx.x * blockDim.x + threadIdx.x;
  int total = 256 * N;
  if (tid >= total) return;
  int j = tid & 7;
  int lane = (tid >> 3) & 63;
  int tile = tid >> 9;
  int NT = N >> 4;
  int nt = tile % NT, kt = tile / NT;
  int k = kt * 32 + ((lane >> 4) << 3) + j;
  int n = nt * 16 + (lane & 15);
  float v = (k < 128) ? Wl[n * 128 + k] : Wr[n * 128 + (k - 128)];
  Wp[tid] = f2b(v);
}

// ---------------- CSR build -------------------------------------------------
__global__ void hist_kernel(const int* __restrict__ dst, int* __restrict__ deg, int nE) {
  int e = blockIdx.x * blockDim.x + threadIdx.x;
  if (e < nE) atomicAdd(&deg[dst[e]], 1);
}

__global__ __launch_bounds__(256) void scan1_kernel(const int* __restrict__ deg,
                                                    int* __restrict__ off,
                                                    int* __restrict__ bsum, int nN) {
  const int t = threadIdx.x;
  const int base = blockIdx.x * 1024 + t * 4;
  int v[4];
  int tsum = 0;
#pragma unroll
  for (int k = 0; k < 4; ++k) {
    v[k] = (base + k < nN) ? deg[base + k] : 0;
    tsum += v[k];
  }
  int lane = t & 63, wid = t >> 6;
  int x = tsum;
#pragma unroll
  for (int d = 1; d < 64; d <<= 1) {
    int y = __shfl_up(x, d);
    if (lane >= d) x += y;
  }
  __shared__ int wsum[4];
  if (lane == 63) wsum[wid] = x;
  __syncthreads();
  int wbase = 0;
  for (int w = 0; w < wid; ++w) wbase += wsum[w];
  int run = wbase + x - tsum;
#pragma unroll
  for (int k = 0; k < 4; ++k) {
    if (base + k < nN) off[base + k] = run;
    run += v[k];
  }
  if (t == 0) bsum[blockIdx.x] = wsum[0] + wsum[1] + wsum[2] + wsum[3];
}

__global__ void scan2_kernel(int* __restrict__ bsum, int nb) {
  if (threadIdx.x == 0 && blockIdx.x == 0) {
    int run = 0;
    for (int i = 0; i < nb; ++i) { int t = bsum[i]; bsum[i] = run; run += t; }
  }
}

__global__ void scan3_kernel(int* __restrict__ off, int* __restrict__ cursor,
                             const int* __restrict__ bsum, int nN) {
  int i = blockIdx.x * blockDim.x + threadIdx.x;
  if (i < nN) {
    int v = off[i] + bsum[i >> 10];
    off[i] = v;
    cursor[i] = v;
  }
}

__global__ void permute_kernel(const int* __restrict__ src, const int* __restrict__ dst,
                               int* __restrict__ cursor, int* __restrict__ esrc, int nE) {
  int e = blockIdx.x * blockDim.x + threadIdx.x;
  if (e < nE) {
    int p = atomicAdd(&cursor[dst[e]], 1);
    esrc[p] = src[e];
  }
}

// ---------------- gather-aggregate (bf16): mean of src rows per node --------
// one 64-lane wave per node; lane q handles features [2q, 2q+1] (one uint).
__global__ __launch_bounds__(256) void gather_mean_kernel(
    const ushort* __restrict__ feat, const int* __restrict__ esrc,
    const int* __restrict__ off, const int* __restrict__ deg,
    ushort* __restrict__ aggm, int nN) {
  const int w = (blockIdx.x * blockDim.x + threadIdx.x) >> 6;
  const int lane = threadIdx.x & 63;
  if (w >= nN) return;
  const int o = off[w];
  const int d = deg[w];
  const unsigned* f = (const unsigned*)feat;
  float ax = 0.0f, ay = 0.0f;
  int i = 0;
  for (; i + 2 <= d; i += 2) {
    int s0 = esrc[o + i];
    int s1 = esrc[o + i + 1];
    unsigned v0 = f[(size_t)s0 * 64 + lane];
    unsigned v1 = f[(size_t)s1 * 64 + lane];
    ax += b2f_lo(v0) + b2f_lo(v1);
    ay += b2f_hi(v0) + b2f_hi(v1);
  }
  if (i < d) {
    unsigned v = f[(size_t)esrc[o + i] * 64 + lane];
    ax += b2f_lo(v);
    ay += b2f_hi(v);
  }
  float inv = 1.0f / fmaxf((float)d, 1.0f);
  unsigned outv = (unsigned)f2b(ax * inv) | ((unsigned)f2b(ay * inv) << 16);
  ((unsigned*)aggm)[(size_t)w * 64 + lane] = outv;
}

// ---------------- layer 1 (MFMA): h = relu([mean||x] @ Wcat + b) ------------
// block = 256 thr = 4 waves; 64 nodes/block; wave w -> rows 16w..16w+15, all 128 cols.
__global__ __launch_bounds__(256) void layer1_mfma(
    const ushort* __restrict__ xb, const ushort* __restrict__ aggb,
    const ushort* __restrict__ Wp, const float* __restrict__ b1,
    ushort* __restrict__ hb, int nN) {
  const int t = threadIdx.x;
  const int wv = t >> 6;
  const int lane = t & 63;
  const int base = blockIdx.x * 64;
  __shared__ ushort As[64][264];  // 256 cols + 8 pad
  for (int i = t; i < 64 * 32; i += 256) {
    int r = i >> 5, cq = i & 31;  // cq = 16B chunk (8 bf16)
    int node = base + r;
    short8 v = {};
    if (node < nN) {
      const ushort* sp = (cq < 16) ? (aggb + (size_t)node * NF + cq * 8)
                                   : (xb + (size_t)node * NF + (cq - 16) * 8);
      v = *(const short8*)sp;
    }
    *(short8*)&As[r][cq * 8] = v;
  }
  __syncthreads();

  f32x4 acc[8] = {};
  const int arow = wv * 16 + (lane & 15);
  const int kq = (lane >> 4) * 8;
#pragma unroll
  for (int kt = 0; kt < 8; ++kt) {
    short8 af = *(const short8*)&As[arow][kt * 32 + kq];
#pragma unroll
    for (int nt = 0; nt < 8; ++nt) {
      short8 bf = *(const short8*)(Wp + ((size_t)(kt * 8 + nt) * 64 + lane) * 8);
      acc[nt] = __builtin_amdgcn_mfma_f32_16x16x32_bf16(af, bf, acc[nt], 0, 0, 0);
    }
  }
  const int quad = lane >> 4;
  const int cl = lane & 15;
#pragma unroll
  for (int nt = 0; nt < 8; ++nt) {
    float bj = b1[nt * 16 + cl];
#pragma unroll
    for (int r = 0; r < 4; ++r) {
      int node = base + wv * 16 + quad * 4 + r;
      if (node < nN) {
        float vv = fmaxf(acc[nt][r] + bj, 0.0f);
        hb[(size_t)node * NF + nt * 16 + cl] = f2b(vv);
      }
    }
  }
}

// ---------------- layer 2 (MFMA) + in-register log_softmax ------------------
__global__ __launch_bounds__(256) void layer2_mfma(
    const ushort* __restrict__ hb, const ushort* __restrict__ aggb,
    const ushort* __restrict__ Wp, const float* __restrict__ b2,
    float* __restrict__ out, int nN) {
  const int t = threadIdx.x;
  const int wv = t >> 6;
  const int lane = t & 63;
  const int base = blockIdx.x * 64;
  __shared__ ushort As[64][264];
  for (int i = t; i < 64 * 32; i += 256) {
    int r = i >> 5, cq = i & 31;
    int node = base + r;
    short8 v = {};
    if (node < nN) {
      const ushort* sp = (cq < 16) ? (aggb + (size_t)node * NF + cq * 8)
                                   : (hb + (size_t)node * NF + (cq - 16) * 8);
      v = *(const short8*)sp;
    }
    *(short8*)&As[r][cq * 8] = v;
  }
  __syncthreads();

  f32x4 acc[4] = {};
  const int arow = wv * 16 + (lane & 15);
  const int kq = (lane >> 4) * 8;
#pragma unroll
  for (int kt = 0; kt < 8; ++kt) {
    short8 af = *(const short8*)&As[arow][kt * 32 + kq];
#pragma unroll
    for (int nt = 0; nt < 4; ++nt) {
      short8 bf = *(const short8*)(Wp + ((size_t)(kt * 4 + nt) * 64 + lane) * 8);
      acc[nt] = __builtin_amdgcn_mfma_f32_16x16x32_bf16(af, bf, acc[nt], 0, 0, 0);
    }
  }
  const int quad = lane >> 4;
  const int cl = lane & 15;
  float bj[4];
#pragma unroll
  for (int nt = 0; nt < 4; ++nt) bj[nt] = b2[nt * 16 + cl];

  // row (quad*4+r) of this wave-tile lives in the 16 lanes of this quad group
#pragma unroll
  for (int r = 0; r < 4; ++r) {
    float v0 = acc[0][r] + bj[0];
    float v1 = acc[1][r] + bj[1];
    float v2 = acc[2][r] + bj[2];
    float v3 = acc[3][r] + bj[3];
    float mx = fmaxf(fmaxf(v0, v1), fmaxf(v2, v3));
#pragma unroll
    for (int s = 1; s < 16; s <<= 1) mx = fmaxf(mx, __shfl_xor(mx, s));
    float sm = expf(v0 - mx) + expf(v1 - mx) + expf(v2 - mx) + expf(v3 - mx);
#pragma unroll
    for (int s = 1; s < 16; s <<= 1) sm += __shfl_xor(sm, s);
    float ls = mx + logf(sm);
    int node = base + wv * 16 + quad * 4 + r;
    if (node < nN) {
      float* op = out + (size_t)node * NC;
      op[0 * 16 + cl] = v0 - ls;
      op[1 * 16 + cl] = v1 - ls;
      op[2 * 16 + cl] = v2 - ls;
      op[3 * 16 + cl] = v3 - ls;
    }
  }
}

extern "C" void kernel_launch(void* const* d_in, const int* in_sizes, int n_in,
                              void* d_out, int out_size, void* d_ws, size_t ws_size,
                              hipStream_t stream) {
  const float* x   = (const float*)d_in[0];
  const int*   ei  = (const int*)d_in[1];
  const float* W1l = (const float*)d_in[2];
  const float* b1l = (const float*)d_in[3];
  const float* W1r = (const float*)d_in[4];
  const float* W2l = (const float*)d_in[5];
  const float* b2l = (const float*)d_in[6];
  const float* W2r = (const float*)d_in[7];
  float* out = (float*)d_out;

  const int nN = in_sizes[0] / NF;  // 100000
  const int nE = in_sizes[1] / 2;   // 1600000
  const int* src = ei;
  const int* dst = ei + nE;

  char* p = (char*)d_ws;
  ushort* xb   = (ushort*)p; p += (size_t)nN * NF * 2;
  ushort* hb   = (ushort*)p; p += (size_t)nN * NF * 2;
  ushort* aggb = (ushort*)p; p += (size_t)nN * NF * 2;
  ushort* Wp1  = (ushort*)p; p += 256 * 128 * 2;
  ushort* Wp2  = (ushort*)p; p += 256 * 64 * 2;
  int* deg  = (int*)p; p += (size_t)nN * 4;
  int* off  = (int*)p; p += (size_t)nN * 4;
  int* cur  = (int*)p; p += (size_t)nN * 4;
  int* bsum = (int*)p; p += 512;
  int* esrc = (int*)p; p += (size_t)nE * 4;

  const int nb1024 = (nN + 1023) / 1024;

  hipMemsetAsync(deg, 0, (size_t)nN * sizeof(int), stream);

  cast_kernel<<<(nN * NF / 4 + 255) / 256, 256, 0, stream>>>(x, xb, nN * NF / 4);
  pack_kernel<<<(256 * 128 + 255) / 256, 256, 0, stream>>>(W1l, W1r, Wp1, 128);
  pack_kernel<<<(256 * 64 + 255) / 256, 256, 0, stream>>>(W2l, W2r, Wp2, 64);

  // --- build CSR by destination ---
  hist_kernel<<<(nE + 255) / 256, 256, 0, stream>>>(dst, deg, nE);
  scan1_kernel<<<nb1024, 256, 0, stream>>>(deg, off, bsum, nN);
  scan2_kernel<<<1, 64, 0, stream>>>(bsum, nb1024);
  scan3_kernel<<<(nN + 255) / 256, 256, 0, stream>>>(off, cur, bsum, nN);
  permute_kernel<<<(nE + 255) / 256, 256, 0, stream>>>(src, dst, cur, esrc, nE);

  // --- layer 1 ---
  gather_mean_kernel<<<(nN + 3) / 4, 256, 0, stream>>>(xb, esrc, off, deg, aggb, nN);
  layer1_mfma<<<(nN + 63) / 64, 256, 0, stream>>>(xb, aggb, Wp1, b1l, hb, nN);

  // --- layer 2 ---
  gather_mean_kernel<<<(nN + 3) / 4, 256, 0, stream>>>(hb, esrc, off, deg, aggb, nN);
  layer2_mfma<<<(nN + 63) / 64, 256, 0, stream>>>(hb, aggb, Wp2, b2l, out, nN);
}

// Round 4
// 501.694 us; speedup vs baseline: 11.6025x; 1.0979x over previous
//
#include <hip/hip_runtime.h>

#define NF 128   // FEATURE == HIDDEN
#define NC 64    // CLASSES

typedef short short8 __attribute__((ext_vector_type(8)));
typedef unsigned short ushort;
typedef float f32x4 __attribute__((ext_vector_type(4)));
typedef unsigned int uint;

__device__ __forceinline__ ushort f2b(float x) {  // RNE float->bf16
  unsigned u = __builtin_bit_cast(unsigned, x);
  u += 0x7fffu + ((u >> 16) & 1u);
  return (ushort)(u >> 16);
}
__device__ __forceinline__ float b2f_lo(unsigned v) {
  return __builtin_bit_cast(float, v << 16);
}
__device__ __forceinline__ float b2f_hi(unsigned v) {
  return __builtin_bit_cast(float, v & 0xffff0000u);
}

// ---------------- cast x (fp32) -> bf16 -------------------------------------
__global__ void cast_kernel(const float* __restrict__ x, ushort* __restrict__ xb, int n4) {
  int i = blockIdx.x * blockDim.x + threadIdx.x;
  if (i >= n4) return;
  float4 v = ((const float4*)x)[i];
  ushort4 o;
  o.x = f2b(v.x); o.y = f2b(v.y); o.z = f2b(v.z); o.w = f2b(v.w);
  ((ushort4*)xb)[i] = o;
}

// ---------------- weight pack: Wcat[k][n] -> MFMA B-fragment order ----------
__global__ void pack_kernel(const float* __restrict__ Wl, const float* __restrict__ Wr,
                            ushort* __restrict__ Wp, int N) {
  int tid = blockIdx.x * blockDim.x + threadIdx.x;
  int total = 256 * N;
  if (tid >= total) return;
  int j = tid & 7;
  int lane = (tid >> 3) & 63;
  int tile = tid >> 9;
  int NT = N >> 4;
  int nt = tile % NT, kt = tile / NT;
  int k = kt * 32 + ((lane >> 4) << 3) + j;
  int n = nt * 16 + (lane & 15);
  float v = (k < 128) ? Wl[n * 128 + k] : Wr[n * 128 + (k - 128)];
  Wp[tid] = f2b(v);
}

// ---------------- CSR build -------------------------------------------------
__global__ void hist_kernel(const int* __restrict__ dst, int* __restrict__ deg, int nE) {
  int t = blockIdx.x * blockDim.x + threadIdx.x;
  int e0 = t * 4;
  if (e0 + 3 < nE) {
    int4 d4 = *(const int4*)(dst + e0);
    atomicAdd(&deg[d4.x], 1);
    atomicAdd(&deg[d4.y], 1);
    atomicAdd(&deg[d4.z], 1);
    atomicAdd(&deg[d4.w], 1);
  } else {
    for (int e = e0; e < nE; ++e) atomicAdd(&deg[dst[e]], 1);
  }
}

__global__ __launch_bounds__(256) void scan1_kernel(const int* __restrict__ deg,
                                                    int* __restrict__ off,
                                                    int* __restrict__ bsum, int nN) {
  const int t = threadIdx.x;
  const int base = blockIdx.x * 1024 + t * 4;
  int v[4];
  int tsum = 0;
#pragma unroll
  for (int k = 0; k < 4; ++k) {
    v[k] = (base + k < nN) ? deg[base + k] : 0;
    tsum += v[k];
  }
  int lane = t & 63, wid = t >> 6;
  int x = tsum;
#pragma unroll
  for (int d = 1; d < 64; d <<= 1) {
    int y = __shfl_up(x, d);
    if (lane >= d) x += y;
  }
  __shared__ int wsum[4];
  if (lane == 63) wsum[wid] = x;
  __syncthreads();
  int wbase = 0;
  for (int w = 0; w < wid; ++w) wbase += wsum[w];
  int run = wbase + x - tsum;
#pragma unroll
  for (int k = 0; k < 4; ++k) {
    if (base + k < nN) off[base + k] = run;
    run += v[k];
  }
  if (t == 0) bsum[blockIdx.x] = wsum[0] + wsum[1] + wsum[2] + wsum[3];
}

// wave-parallel exclusive scan of block sums (nb <= 128), one 64-lane wave
__global__ void scan2_kernel(int* __restrict__ bsum, int nb) {
  int lane = threadIdx.x;
  int i0 = 2 * lane, i1 = 2 * lane + 1;
  int v0 = (i0 < nb) ? bsum[i0] : 0;
  int v1 = (i1 < nb) ? bsum[i1] : 0;
  int s = v0 + v1;
  int x = s;
#pragma unroll
  for (int d = 1; d < 64; d <<= 1) {
    int y = __shfl_up(x, d);
    if (lane >= d) x += y;
  }
  int ex = x - s;
  if (i0 < nb) bsum[i0] = ex;
  if (i1 < nb) bsum[i1] = ex + v0;
}

__global__ void scan3_kernel(int* __restrict__ off, int* __restrict__ cursor,
                             const int* __restrict__ bsum, int nN) {
  int i = blockIdx.x * blockDim.x + threadIdx.x;
  if (i < nN) {
    int v = off[i] + bsum[i >> 10];
    off[i] = v;
    cursor[i] = v;
  }
}

// permute: esrc sorted by dst. 4 edges/thread for latency hiding.
__global__ void permute_kernel(const int* __restrict__ src, const int* __restrict__ dst,
                               int* __restrict__ cursor, int* __restrict__ esrc, int nE) {
  int t = blockIdx.x * blockDim.x + threadIdx.x;
  int e0 = t * 4;
  if (e0 + 3 < nE) {
    int4 d4 = *(const int4*)(dst + e0);
    int4 s4 = *(const int4*)(src + e0);
    int p0 = atomicAdd(&cursor[d4.x], 1);
    int p1 = atomicAdd(&cursor[d4.y], 1);
    int p2 = atomicAdd(&cursor[d4.z], 1);
    int p3 = atomicAdd(&cursor[d4.w], 1);
    esrc[p0] = s4.x;
    esrc[p1] = s4.y;
    esrc[p2] = s4.z;
    esrc[p3] = s4.w;
  } else {
    for (int e = e0; e < nE; ++e) {
      int p = atomicAdd(&cursor[dst[e]], 1);
      esrc[p] = src[e];
    }
  }
}

// ---------------- gather-aggregate (bf16): mean of src rows per node --------
// one wave per node; 4 edges in flight (lane group g = lane>>4), 16B/lane:
// lane (g,l) loads 16-byte chunk l of the row of edge i+g.
__global__ __launch_bounds__(256) void gather_mean_kernel(
    const ushort* __restrict__ feat, const int* __restrict__ esrc,
    const int* __restrict__ off, const int* __restrict__ deg,
    ushort* __restrict__ aggm, int nN) {
  const int w = (blockIdx.x * blockDim.x + threadIdx.x) >> 6;
  const int lane = threadIdx.x & 63;
  if (w >= nN) return;
  const int o = off[w];
  const int d = deg[w];
  const int g = lane >> 4;
  const int l = lane & 15;
  float acc[8] = {0.f, 0.f, 0.f, 0.f, 0.f, 0.f, 0.f, 0.f};
  int i = 0;
  for (; i + 4 <= d; i += 4) {
    int s = esrc[o + i + g];
    uint4 v = ((const uint4*)(feat + (size_t)s * NF))[l];
    acc[0] += b2f_lo(v.x); acc[1] += b2f_hi(v.x);
    acc[2] += b2f_lo(v.y); acc[3] += b2f_hi(v.y);
    acc[4] += b2f_lo(v.z); acc[5] += b2f_hi(v.z);
    acc[6] += b2f_lo(v.w); acc[7] += b2f_hi(v.w);
  }
  if (i + g < d) {
    int s = esrc[o + i + g];
    uint4 v = ((const uint4*)(feat + (size_t)s * NF))[l];
    acc[0] += b2f_lo(v.x); acc[1] += b2f_hi(v.x);
    acc[2] += b2f_lo(v.y); acc[3] += b2f_hi(v.y);
    acc[4] += b2f_lo(v.z); acc[5] += b2f_hi(v.z);
    acc[6] += b2f_lo(v.w); acc[7] += b2f_hi(v.w);
  }
  // reduce across the 4 lane groups (same chunk l lives in lanes l, l+16, l+32, l+48)
#pragma unroll
  for (int k = 0; k < 8; ++k) {
    acc[k] += __shfl_xor(acc[k], 16);
    acc[k] += __shfl_xor(acc[k], 32);
  }
  if (g == 0) {
    float inv = 1.0f / fmaxf((float)d, 1.0f);
    uint4 ov;
    ov.x = (uint)f2b(acc[0] * inv) | ((uint)f2b(acc[1] * inv) << 16);
    ov.y = (uint)f2b(acc[2] * inv) | ((uint)f2b(acc[3] * inv) << 16);
    ov.z = (uint)f2b(acc[4] * inv) | ((uint)f2b(acc[5] * inv) << 16);
    ov.w = (uint)f2b(acc[6] * inv) | ((uint)f2b(acc[7] * inv) << 16);
    ((uint4*)(aggm + (size_t)w * NF))[l] = ov;
  }
}

// ---------------- layer 1 (MFMA): h = relu([mean||x] @ Wcat + b) ------------
__global__ __launch_bounds__(256) void layer1_mfma(
    const ushort* __restrict__ xb, const ushort* __restrict__ aggb,
    const ushort* __restrict__ Wp, const float* __restrict__ b1,
    ushort* __restrict__ hb, int nN) {
  const int t = threadIdx.x;
  const int wv = t >> 6;
  const int lane = t & 63;
  const int base = blockIdx.x * 64;
  __shared__ ushort As[64][264];  // 256 cols + 8 pad
  for (int i = t; i < 64 * 32; i += 256) {
    int r = i >> 5, cq = i & 31;
    int node = base + r;
    short8 v = {};
    if (node < nN) {
      const ushort* sp = (cq < 16) ? (aggb + (size_t)node * NF + cq * 8)
                                   : (xb + (size_t)node * NF + (cq - 16) * 8);
      v = *(const short8*)sp;
    }
    *(short8*)&As[r][cq * 8] = v;
  }
  __syncthreads();

  f32x4 acc[8] = {};
  const int arow = wv * 16 + (lane & 15);
  const int kq = (lane >> 4) * 8;
#pragma unroll
  for (int kt = 0; kt < 8; ++kt) {
    short8 af = *(const short8*)&As[arow][kt * 32 + kq];
#pragma unroll
    for (int nt = 0; nt < 8; ++nt) {
      short8 bf = *(const short8*)(Wp + ((size_t)(kt * 8 + nt) * 64 + lane) * 8);
      acc[nt] = __builtin_amdgcn_mfma_f32_16x16x32_bf16(af, bf, acc[nt], 0, 0, 0);
    }
  }
  const int quad = lane >> 4;
  const int cl = lane & 15;
#pragma unroll
  for (int nt = 0; nt < 8; ++nt) {
    float bj = b1[nt * 16 + cl];
#pragma unroll
    for (int r = 0; r < 4; ++r) {
      int node = base + wv * 16 + quad * 4 + r;
      if (node < nN) {
        float vv = fmaxf(acc[nt][r] + bj, 0.0f);
        hb[(size_t)node * NF + nt * 16 + cl] = f2b(vv);
      }
    }
  }
}

// ---------------- layer 2 (MFMA) + in-register log_softmax ------------------
__global__ __launch_bounds__(256) void layer2_mfma(
    const ushort* __restrict__ hb, const ushort* __restrict__ aggb,
    const ushort* __restrict__ Wp, const float* __restrict__ b2,
    float* __restrict__ out, int nN) {
  const int t = threadIdx.x;
  const int wv = t >> 6;
  const int lane = t & 63;
  const int base = blockIdx.x * 64;
  __shared__ ushort As[64][264];
  for (int i = t; i < 64 * 32; i += 256) {
    int r = i >> 5, cq = i & 31;
    int node = base + r;
    short8 v = {};
    if (node < nN) {
      const ushort* sp = (cq < 16) ? (aggb + (size_t)node * NF + cq * 8)
                                   : (hb + (size_t)node * NF + (cq - 16) * 8);
      v = *(const short8*)sp;
    }
    *(short8*)&As[r][cq * 8] = v;
  }
  __syncthreads();

  f32x4 acc[4] = {};
  const int arow = wv * 16 + (lane & 15);
  const int kq = (lane >> 4) * 8;
#pragma unroll
  for (int kt = 0; kt < 8; ++kt) {
    short8 af = *(const short8*)&As[arow][kt * 32 + kq];
#pragma unroll
    for (int nt = 0; nt < 4; ++nt) {
      short8 bf = *(const short8*)(Wp + ((size_t)(kt * 4 + nt) * 64 + lane) * 8);
      acc[nt] = __builtin_amdgcn_mfma_f32_16x16x32_bf16(af, bf, acc[nt], 0, 0, 0);
    }
  }
  const int quad = lane >> 4;
  const int cl = lane & 15;
  float bj[4];
#pragma unroll
  for (int nt = 0; nt < 4; ++nt) bj[nt] = b2[nt * 16 + cl];

#pragma unroll
  for (int r = 0; r < 4; ++r) {
    float v0 = acc[0][r] + bj[0];
    float v1 = acc[1][r] + bj[1];
    float v2 = acc[2][r] + bj[2];
    float v3 = acc[3][r] + bj[3];
    float mx = fmaxf(fmaxf(v0, v1), fmaxf(v2, v3));
#pragma unroll
    for (int s = 1; s < 16; s <<= 1) mx = fmaxf(mx, __shfl_xor(mx, s));
    float sm = expf(v0 - mx) + expf(v1 - mx) + expf(v2 - mx) + expf(v3 - mx);
#pragma unroll
    for (int s = 1; s < 16; s <<= 1) sm += __shfl_xor(sm, s);
    float ls = mx + logf(sm);
    int node = base + wv * 16 + quad * 4 + r;
    if (node < nN) {
      float* op = out + (size_t)node * NC;
      op[0 * 16 + cl] = v0 - ls;
      op[1 * 16 + cl] = v1 - ls;
      op[2 * 16 + cl] = v2 - ls;
      op[3 * 16 + cl] = v3 - ls;
    }
  }
}

extern "C" void kernel_launch(void* const* d_in, const int* in_sizes, int n_in,
                              void* d_out, int out_size, void* d_ws, size_t ws_size,
                              hipStream_t stream) {
  const float* x   = (const float*)d_in[0];
  const int*   ei  = (const int*)d_in[1];
  const float* W1l = (const float*)d_in[2];
  const float* b1l = (const float*)d_in[3];
  const float* W1r = (const float*)d_in[4];
  const float* W2l = (const float*)d_in[5];
  const float* b2l = (const float*)d_in[6];
  const float* W2r = (const float*)d_in[7];
  float* out = (float*)d_out;

  const int nN = in_sizes[0] / NF;  // 100000
  const int nE = in_sizes[1] / 2;   // 1600000
  const int* src = ei;
  const int* dst = ei + nE;

  char* p = (char*)d_ws;
  ushort* xb   = (ushort*)p; p += (size_t)nN * NF * 2;
  ushort* hb   = (ushort*)p; p += (size_t)nN * NF * 2;
  ushort* aggb = (ushort*)p; p += (size_t)nN * NF * 2;
  ushort* Wp1  = (ushort*)p; p += 256 * 128 * 2;
  ushort* Wp2  = (ushort*)p; p += 256 * 64 * 2;
  int* deg  = (int*)p; p += (size_t)nN * 4;
  int* off  = (int*)p; p += (size_t)nN * 4;
  int* cur  = (int*)p; p += (size_t)nN * 4;
  int* bsum = (int*)p; p += 512;
  int* esrc = (int*)p; p += (size_t)nE * 4;

  const int nb1024 = (nN + 1023) / 1024;

  hipMemsetAsync(deg, 0, (size_t)nN * sizeof(int), stream);

  cast_kernel<<<(nN * NF / 4 + 255) / 256, 256, 0, stream>>>(x, xb, nN * NF / 4);
  pack_kernel<<<(256 * 128 + 255) / 256, 256, 0, stream>>>(W1l, W1r, Wp1, 128);
  pack_kernel<<<(256 * 64 + 255) / 256, 256, 0, stream>>>(W2l, W2r, Wp2, 64);

  // --- build CSR by destination ---
  hist_kernel<<<(nE / 4 + 255) / 256, 256, 0, stream>>>(dst, deg, nE);
  scan1_kernel<<<nb1024, 256, 0, stream>>>(deg, off, bsum, nN);
  scan2_kernel<<<1, 64, 0, stream>>>(bsum, nb1024);
  scan3_kernel<<<(nN + 255) / 256, 256, 0, stream>>>(off, cur, bsum, nN);
  permute_kernel<<<(nE / 4 + 255) / 256, 256, 0, stream>>>(src, dst, cur, esrc, nE);

  // --- layer 1 ---
  gather_mean_kernel<<<(nN + 3) / 4, 256, 0, stream>>>(xb, esrc, off, deg, aggb, nN);
  layer1_mfma<<<(nN + 63) / 64, 256, 0, stream>>>(xb, aggb, Wp1, b1l, hb, nN);

  // --- layer 2 ---
  gather_mean_kernel<<<(nN + 3) / 4, 256, 0, stream>>>(hb, esrc, off, deg, aggb, nN);
  layer2_mfma<<<(nN + 63) / 64, 256, 0, stream>>>(hb, aggb, Wp2, b2l, out, nN);
}

// Round 5
// 407.943 us; speedup vs baseline: 14.2690x; 1.2298x over previous
//
#include <hip/hip_runtime.h>

#define NF 128   // FEATURE == HIDDEN
#define NC 64    // CLASSES

typedef short short8 __attribute__((ext_vector_type(8)));
typedef unsigned short ushort;
typedef float f32x4 __attribute__((ext_vector_type(4)));
typedef unsigned int uint;

__device__ __forceinline__ ushort f2b(float x) {  // RNE float->bf16
  unsigned u = __builtin_bit_cast(unsigned, x);
  u += 0x7fffu + ((u >> 16) & 1u);
  return (ushort)(u >> 16);
}
__device__ __forceinline__ float b2f_lo(unsigned v) {
  return __builtin_bit_cast(float, v << 16);
}
__device__ __forceinline__ float b2f_hi(unsigned v) {
  return __builtin_bit_cast(float, v & 0xffff0000u);
}

// ---------------- cast x (fp32) -> bf16 -------------------------------------
__global__ void cast_kernel(const float* __restrict__ x, ushort* __restrict__ xb, int n4) {
  int i = blockIdx.x * blockDim.x + threadIdx.x;
  if (i >= n4) return;
  float4 v = ((const float4*)x)[i];
  ushort4 o;
  o.x = f2b(v.x); o.y = f2b(v.y); o.z = f2b(v.z); o.w = f2b(v.w);
  ((ushort4*)xb)[i] = o;
}

// ---------------- weight pack: Wcat[k][n] -> MFMA B-fragment order ----------
__global__ void pack_kernel(const float* __restrict__ Wl, const float* __restrict__ Wr,
                            ushort* __restrict__ Wp, int N) {
  int tid = blockIdx.x * blockDim.x + threadIdx.x;
  int total = 256 * N;
  if (tid >= total) return;
  int j = tid & 7;
  int lane = (tid >> 3) & 63;
  int tile = tid >> 9;
  int NT = N >> 4;
  int nt = tile % NT, kt = tile / NT;
  int k = kt * 32 + ((lane >> 4) << 3) + j;
  int n = nt * 16 + (lane & 15);
  float v = (k < 128) ? Wl[n * 128 + k] : Wr[n * 128 + (k - 128)];
  Wp[tid] = f2b(v);
}

// ---------------- CSR build: histogram of dst + intra-node rank -------------
__global__ void hist_kernel(const int* __restrict__ dst, int* __restrict__ deg,
                            int* __restrict__ rank, int nE) {
  int t = blockIdx.x * blockDim.x + threadIdx.x;
  int e0 = t * 4;
  if (e0 + 3 < nE) {
    int4 d4 = *(const int4*)(dst + e0);
    int4 r4;
    r4.x = atomicAdd(&deg[d4.x], 1);
    r4.y = atomicAdd(&deg[d4.y], 1);
    r4.z = atomicAdd(&deg[d4.z], 1);
    r4.w = atomicAdd(&deg[d4.w], 1);
    *(int4*)(rank + e0) = r4;
  } else {
    for (int e = e0; e < nE; ++e) rank[e] = atomicAdd(&deg[dst[e]], 1);
  }
}

__global__ __launch_bounds__(256) void scan1_kernel(const int* __restrict__ deg,
                                                    int* __restrict__ off,
                                                    int* __restrict__ bsum, int nN) {
  const int t = threadIdx.x;
  const int base = blockIdx.x * 1024 + t * 4;
  int v[4];
  int tsum = 0;
#pragma unroll
  for (int k = 0; k < 4; ++k) {
    v[k] = (base + k < nN) ? deg[base + k] : 0;
    tsum += v[k];
  }
  int lane = t & 63, wid = t >> 6;
  int x = tsum;
#pragma unroll
  for (int d = 1; d < 64; d <<= 1) {
    int y = __shfl_up(x, d);
    if (lane >= d) x += y;
  }
  __shared__ int wsum[4];
  if (lane == 63) wsum[wid] = x;
  __syncthreads();
  int wbase = 0;
  for (int w = 0; w < wid; ++w) wbase += wsum[w];
  int run = wbase + x - tsum;
#pragma unroll
  for (int k = 0; k < 4; ++k) {
    if (base + k < nN) off[base + k] = run;
    run += v[k];
  }
  if (t == 0) bsum[blockIdx.x] = wsum[0] + wsum[1] + wsum[2] + wsum[3];
}

// wave-parallel exclusive scan of block sums (nb <= 128), one 64-lane wave
__global__ void scan2_kernel(int* __restrict__ bsum, int nb) {
  int lane = threadIdx.x;
  int i0 = 2 * lane, i1 = 2 * lane + 1;
  int v0 = (i0 < nb) ? bsum[i0] : 0;
  int v1 = (i1 < nb) ? bsum[i1] : 0;
  int s = v0 + v1;
  int x = s;
#pragma unroll
  for (int d = 1; d < 64; d <<= 1) {
    int y = __shfl_up(x, d);
    if (lane >= d) x += y;
  }
  int ex = x - s;
  if (i0 < nb) bsum[i0] = ex;
  if (i1 < nb) bsum[i1] = ex + v0;
}

__global__ void scan3_kernel(int* __restrict__ off, const int* __restrict__ bsum, int nN) {
  int i = blockIdx.x * blockDim.x + threadIdx.x;
  if (i < nN) off[i] += bsum[i >> 10];
}

// permute (atomic-free): esrc[off[dst[e]] + rank[e]] = src[e]
__global__ void permute_kernel(const int* __restrict__ src, const int* __restrict__ dst,
                               const int* __restrict__ rank, const int* __restrict__ off,
                               int* __restrict__ esrc, int nE) {
  int t = blockIdx.x * blockDim.x + threadIdx.x;
  int e0 = t * 4;
  if (e0 + 3 < nE) {
    int4 d4 = *(const int4*)(dst + e0);
    int4 r4 = *(const int4*)(rank + e0);
    int4 s4 = *(const int4*)(src + e0);
    int p0 = off[d4.x] + r4.x;
    int p1 = off[d4.y] + r4.y;
    int p2 = off[d4.z] + r4.z;
    int p3 = off[d4.w] + r4.w;
    esrc[p0] = s4.x;
    esrc[p1] = s4.y;
    esrc[p2] = s4.z;
    esrc[p3] = s4.w;
  } else {
    for (int e = e0; e < nE; ++e) esrc[off[dst[e]] + rank[e]] = src[e];
  }
}

// ---------------- gather-aggregate (bf16): mean of src rows per node --------
// one wave per node; 4 edges in flight (lane group g = lane>>4), 16B/lane.
__global__ __launch_bounds__(256) void gather_mean_kernel(
    const ushort* __restrict__ feat, const int* __restrict__ esrc,
    const int* __restrict__ off, const int* __restrict__ deg,
    ushort* __restrict__ aggm, int nN) {
  const int w = (blockIdx.x * blockDim.x + threadIdx.x) >> 6;
  const int lane = threadIdx.x & 63;
  if (w >= nN) return;
  const int o = off[w];
  const int d = deg[w];
  const int g = lane >> 4;
  const int l = lane & 15;
  float acc[8] = {0.f, 0.f, 0.f, 0.f, 0.f, 0.f, 0.f, 0.f};
  int i = 0;
  for (; i + 4 <= d; i += 4) {
    int s = esrc[o + i + g];
    uint4 v = ((const uint4*)(feat + (size_t)s * NF))[l];
    acc[0] += b2f_lo(v.x); acc[1] += b2f_hi(v.x);
    acc[2] += b2f_lo(v.y); acc[3] += b2f_hi(v.y);
    acc[4] += b2f_lo(v.z); acc[5] += b2f_hi(v.z);
    acc[6] += b2f_lo(v.w); acc[7] += b2f_hi(v.w);
  }
  if (i + g < d) {
    int s = esrc[o + i + g];
    uint4 v = ((const uint4*)(feat + (size_t)s * NF))[l];
    acc[0] += b2f_lo(v.x); acc[1] += b2f_hi(v.x);
    acc[2] += b2f_lo(v.y); acc[3] += b2f_hi(v.y);
    acc[4] += b2f_lo(v.z); acc[5] += b2f_hi(v.z);
    acc[6] += b2f_lo(v.w); acc[7] += b2f_hi(v.w);
  }
#pragma unroll
  for (int k = 0; k < 8; ++k) {
    acc[k] += __shfl_xor(acc[k], 16);
    acc[k] += __shfl_xor(acc[k], 32);
  }
  if (g == 0) {
    float inv = 1.0f / fmaxf((float)d, 1.0f);
    uint4 ov;
    ov.x = (uint)f2b(acc[0] * inv) | ((uint)f2b(acc[1] * inv) << 16);
    ov.y = (uint)f2b(acc[2] * inv) | ((uint)f2b(acc[3] * inv) << 16);
    ov.z = (uint)f2b(acc[4] * inv) | ((uint)f2b(acc[5] * inv) << 16);
    ov.w = (uint)f2b(acc[6] * inv) | ((uint)f2b(acc[7] * inv) << 16);
    ((uint4*)(aggm + (size_t)w * NF))[l] = ov;
  }
}

// ---------------- layer 1 (MFMA): h = relu([mean||x] @ Wcat + b) ------------
__global__ __launch_bounds__(256) void layer1_mfma(
    const ushort* __restrict__ xb, const ushort* __restrict__ aggb,
    const ushort* __restrict__ Wp, const float* __restrict__ b1,
    ushort* __restrict__ hb, int nN) {
  const int t = threadIdx.x;
  const int wv = t >> 6;
  const int lane = t & 63;
  const int base = blockIdx.x * 64;
  __shared__ ushort As[64][264];  // 256 cols + 8 pad
  for (int i = t; i < 64 * 32; i += 256) {
    int r = i >> 5, cq = i & 31;
    int node = base + r;
    short8 v = {};
    if (node < nN) {
      const ushort* sp = (cq < 16) ? (aggb + (size_t)node * NF + cq * 8)
                                   : (xb + (size_t)node * NF + (cq - 16) * 8);
      v = *(const short8*)sp;
    }
    *(short8*)&As[r][cq * 8] = v;
  }
  __syncthreads();

  f32x4 acc[8] = {};
  const int arow = wv * 16 + (lane & 15);
  const int kq = (lane >> 4) * 8;
#pragma unroll
  for (int kt = 0; kt < 8; ++kt) {
    short8 af = *(const short8*)&As[arow][kt * 32 + kq];
#pragma unroll
    for (int nt = 0; nt < 8; ++nt) {
      short8 bf = *(const short8*)(Wp + ((size_t)(kt * 8 + nt) * 64 + lane) * 8);
      acc[nt] = __builtin_amdgcn_mfma_f32_16x16x32_bf16(af, bf, acc[nt], 0, 0, 0);
    }
  }
  const int quad = lane >> 4;
  const int cl = lane & 15;
#pragma unroll
  for (int nt = 0; nt < 8; ++nt) {
    float bj = b1[nt * 16 + cl];
#pragma unroll
    for (int r = 0; r < 4; ++r) {
      int node = base + wv * 16 + quad * 4 + r;
      if (node < nN) {
        float vv = fmaxf(acc[nt][r] + bj, 0.0f);
        hb[(size_t)node * NF + nt * 16 + cl] = f2b(vv);
      }
    }
  }
}

// ---------------- layer 2 (MFMA) + in-register log_softmax ------------------
__global__ __launch_bounds__(256) void layer2_mfma(
    const ushort* __restrict__ hb, const ushort* __restrict__ aggb,
    const ushort* __restrict__ Wp, const float* __restrict__ b2,
    float* __restrict__ out, int nN) {
  const int t = threadIdx.x;
  const int wv = t >> 6;
  const int lane = t & 63;
  const int base = blockIdx.x * 64;
  __shared__ ushort As[64][264];
  for (int i = t; i < 64 * 32; i += 256) {
    int r = i >> 5, cq = i & 31;
    int node = base + r;
    short8 v = {};
    if (node < nN) {
      const ushort* sp = (cq < 16) ? (aggb + (size_t)node * NF + cq * 8)
                                   : (hb + (size_t)node * NF + (cq - 16) * 8);
      v = *(const short8*)sp;
    }
    *(short8*)&As[r][cq * 8] = v;
  }
  __syncthreads();

  f32x4 acc[4] = {};
  const int arow = wv * 16 + (lane & 15);
  const int kq = (lane >> 4) * 8;
#pragma unroll
  for (int kt = 0; kt < 8; ++kt) {
    short8 af = *(const short8*)&As[arow][kt * 32 + kq];
#pragma unroll
    for (int nt = 0; nt < 4; ++nt) {
      short8 bf = *(const short8*)(Wp + ((size_t)(kt * 4 + nt) * 64 + lane) * 8);
      acc[nt] = __builtin_amdgcn_mfma_f32_16x16x32_bf16(af, bf, acc[nt], 0, 0, 0);
    }
  }
  const int quad = lane >> 4;
  const int cl = lane & 15;
  float bj[4];
#pragma unroll
  for (int nt = 0; nt < 4; ++nt) bj[nt] = b2[nt * 16 + cl];

#pragma unroll
  for (int r = 0; r < 4; ++r) {
    float v0 = acc[0][r] + bj[0];
    float v1 = acc[1][r] + bj[1];
    float v2 = acc[2][r] + bj[2];
    float v3 = acc[3][r] + bj[3];
    float mx = fmaxf(fmaxf(v0, v1), fmaxf(v2, v3));
#pragma unroll
    for (int s = 1; s < 16; s <<= 1) mx = fmaxf(mx, __shfl_xor(mx, s));
    float sm = expf(v0 - mx) + expf(v1 - mx) + expf(v2 - mx) + expf(v3 - mx);
#pragma unroll
    for (int s = 1; s < 16; s <<= 1) sm += __shfl_xor(sm, s);
    float ls = mx + logf(sm);
    int node = base + wv * 16 + quad * 4 + r;
    if (node < nN) {
      float* op = out + (size_t)node * NC;
      op[0 * 16 + cl] = v0 - ls;
      op[1 * 16 + cl] = v1 - ls;
      op[2 * 16 + cl] = v2 - ls;
      op[3 * 16 + cl] = v3 - ls;
    }
  }
}

extern "C" void kernel_launch(void* const* d_in, const int* in_sizes, int n_in,
                              void* d_out, int out_size, void* d_ws, size_t ws_size,
                              hipStream_t stream) {
  const float* x   = (const float*)d_in[0];
  const int*   ei  = (const int*)d_in[1];
  const float* W1l = (const float*)d_in[2];
  const float* b1l = (const float*)d_in[3];
  const float* W1r = (const float*)d_in[4];
  const float* W2l = (const float*)d_in[5];
  const float* b2l = (const float*)d_in[6];
  const float* W2r = (const float*)d_in[7];
  float* out = (float*)d_out;

  const int nN = in_sizes[0] / NF;  // 100000
  const int nE = in_sizes[1] / 2;   // 1600000
  const int* src = ei;
  const int* dst = ei + nE;

  char* p = (char*)d_ws;
  ushort* xb   = (ushort*)p; p += (size_t)nN * NF * 2;
  ushort* hb   = (ushort*)p; p += (size_t)nN * NF * 2;
  ushort* aggb = (ushort*)p; p += (size_t)nN * NF * 2;
  ushort* Wp1  = (ushort*)p; p += 256 * 128 * 2;
  ushort* Wp2  = (ushort*)p; p += 256 * 64 * 2;
  int* deg  = (int*)p; p += (size_t)nN * 4;
  int* off  = (int*)p; p += (size_t)nN * 4;
  int* bsum = (int*)p; p += 512;
  int* esrc = (int*)p; p += (size_t)nE * 4;
  int* rank = (int*)p; p += (size_t)nE * 4;

  const int nb1024 = (nN + 1023) / 1024;

  hipMemsetAsync(deg, 0, (size_t)nN * sizeof(int), stream);

  cast_kernel<<<(nN * NF / 4 + 255) / 256, 256, 0, stream>>>(x, xb, nN * NF / 4);
  pack_kernel<<<(256 * 128 + 255) / 256, 256, 0, stream>>>(W1l, W1r, Wp1, 128);
  pack_kernel<<<(256 * 64 + 255) / 256, 256, 0, stream>>>(W2l, W2r, Wp2, 64);

  // --- build CSR by destination ---
  hist_kernel<<<(nE / 4 + 255) / 256, 256, 0, stream>>>(dst, deg, rank, nE);
  scan1_kernel<<<nb1024, 256, 0, stream>>>(deg, off, bsum, nN);
  scan2_kernel<<<1, 64, 0, stream>>>(bsum, nb1024);
  scan3_kernel<<<(nN + 255) / 256, 256, 0, stream>>>(off, bsum, nN);
  permute_kernel<<<(nE / 4 + 255) / 256, 256, 0, stream>>>(src, dst, rank, off, esrc, nE);

  // --- layer 1 ---
  gather_mean_kernel<<<(nN + 3) / 4, 256, 0, stream>>>(xb, esrc, off, deg, aggb, nN);
  layer1_mfma<<<(nN + 63) / 64, 256, 0, stream>>>(xb, aggb, Wp1, b1l, hb, nN);

  // --- layer 2 ---
  gather_mean_kernel<<<(nN + 3) / 4, 256, 0, stream>>>(hb, esrc, off, deg, aggb, nN);
  layer2_mfma<<<(nN + 63) / 64, 256, 0, stream>>>(hb, aggb, Wp2, b2l, out, nN);
}

// Round 6
// 391.694 us; speedup vs baseline: 14.8609x; 1.0415x over previous
//
#include <hip/hip_runtime.h>

#define NF 128   // FEATURE == HIDDEN
#define NC 64    // CLASSES

typedef short short8 __attribute__((ext_vector_type(8)));
typedef unsigned short ushort;
typedef float f32x4 __attribute__((ext_vector_type(4)));
typedef unsigned int uint;

__device__ __forceinline__ ushort f2b(float x) {  // RNE float->bf16
  unsigned u = __builtin_bit_cast(unsigned, x);
  u += 0x7fffu + ((u >> 16) & 1u);
  return (ushort)(u >> 16);
}
__device__ __forceinline__ float b2f_lo(unsigned v) {
  return __builtin_bit_cast(float, v << 16);
}
__device__ __forceinline__ float b2f_hi(unsigned v) {
  return __builtin_bit_cast(float, v & 0xffff0000u);
}

// ---------------- cast x (fp32) -> bf16 -------------------------------------
__global__ void cast_kernel(const float* __restrict__ x, ushort* __restrict__ xb, int n4) {
  int i = blockIdx.x * blockDim.x + threadIdx.x;
  if (i >= n4) return;
  float4 v = ((const float4*)x)[i];
  ushort4 o;
  o.x = f2b(v.x); o.y = f2b(v.y); o.z = f2b(v.z); o.w = f2b(v.w);
  ((ushort4*)xb)[i] = o;
}

// ---------------- weight pack: [Wl||Wr] (K=256) -> MFMA B-frag (layer 1) ----
__global__ void pack1_kernel(const float* __restrict__ Wl, const float* __restrict__ Wr,
                             ushort* __restrict__ Wp, int N) {
  int tid = blockIdx.x * blockDim.x + threadIdx.x;
  int total = 256 * N;
  if (tid >= total) return;
  int j = tid & 7;
  int lane = (tid >> 3) & 63;
  int tile = tid >> 9;
  int NT = N >> 4;
  int nt = tile % NT, kt = tile / NT;
  int k = kt * 32 + ((lane >> 4) << 3) + j;
  int n = nt * 16 + (lane & 15);
  float v = (k < 128) ? Wl[n * 128 + k] : Wr[n * 128 + (k - 128)];
  Wp[tid] = f2b(v);
}

// ---------------- weight pack: single W (64x128, K=128) -> MFMA B-frag ------
// handles W2l -> Wpa and W2r -> Wpb in one launch (8192 elements each)
__global__ void pack2_kernel(const float* __restrict__ Wa, const float* __restrict__ Wb,
                             ushort* __restrict__ Wpa, ushort* __restrict__ Wpb) {
  int tid0 = blockIdx.x * blockDim.x + threadIdx.x;
  if (tid0 >= 2 * 8192) return;
  int which = tid0 >> 13;
  int tid = tid0 & 8191;
  int j = tid & 7;
  int lane = (tid >> 3) & 63;
  int tile = tid >> 9;              // 0..15
  int nt = tile & 3, kt = tile >> 2;
  int k = kt * 32 + ((lane >> 4) << 3) + j;   // 0..127
  int n = nt * 16 + (lane & 15);              // 0..63
  const float* W = which ? Wb : Wa;
  ushort* Wp = which ? Wpb : Wpa;
  Wp[tid] = f2b(W[n * 128 + k]);
}

// ---------------- CSR build: histogram of dst + intra-node rank (8-ILP) -----
__global__ void hist_kernel(const int* __restrict__ dst, int* __restrict__ deg,
                            int* __restrict__ rank, int nE) {
  int t = blockIdx.x * blockDim.x + threadIdx.x;
  int e0 = t * 8;
  if (e0 + 7 < nE) {
    int4 a = *(const int4*)(dst + e0);
    int4 b = *(const int4*)(dst + e0 + 4);
    int4 ra, rb;
    ra.x = atomicAdd(&deg[a.x], 1);
    ra.y = atomicAdd(&deg[a.y], 1);
    ra.z = atomicAdd(&deg[a.z], 1);
    ra.w = atomicAdd(&deg[a.w], 1);
    rb.x = atomicAdd(&deg[b.x], 1);
    rb.y = atomicAdd(&deg[b.y], 1);
    rb.z = atomicAdd(&deg[b.z], 1);
    rb.w = atomicAdd(&deg[b.w], 1);
    *(int4*)(rank + e0) = ra;
    *(int4*)(rank + e0 + 4) = rb;
  } else {
    for (int e = e0; e < nE; ++e) rank[e] = atomicAdd(&deg[dst[e]], 1);
  }
}

__global__ __launch_bounds__(256) void scan1_kernel(const int* __restrict__ deg,
                                                    int* __restrict__ off,
                                                    int* __restrict__ bsum, int nN) {
  const int t = threadIdx.x;
  const int base = blockIdx.x * 1024 + t * 4;
  int v[4];
  int tsum = 0;
#pragma unroll
  for (int k = 0; k < 4; ++k) {
    v[k] = (base + k < nN) ? deg[base + k] : 0;
    tsum += v[k];
  }
  int lane = t & 63, wid = t >> 6;
  int x = tsum;
#pragma unroll
  for (int d = 1; d < 64; d <<= 1) {
    int y = __shfl_up(x, d);
    if (lane >= d) x += y;
  }
  __shared__ int wsum[4];
  if (lane == 63) wsum[wid] = x;
  __syncthreads();
  int wbase = 0;
  for (int w = 0; w < wid; ++w) wbase += wsum[w];
  int run = wbase + x - tsum;
#pragma unroll
  for (int k = 0; k < 4; ++k) {
    if (base + k < nN) off[base + k] = run;
    run += v[k];
  }
  if (t == 0) bsum[blockIdx.x] = wsum[0] + wsum[1] + wsum[2] + wsum[3];
}

// wave-parallel exclusive scan of block sums (nb <= 128), one 64-lane wave
__global__ void scan2_kernel(int* __restrict__ bsum, int nb) {
  int lane = threadIdx.x;
  int i0 = 2 * lane, i1 = 2 * lane + 1;
  int v0 = (i0 < nb) ? bsum[i0] : 0;
  int v1 = (i1 < nb) ? bsum[i1] : 0;
  int s = v0 + v1;
  int x = s;
#pragma unroll
  for (int d = 1; d < 64; d <<= 1) {
    int y = __shfl_up(x, d);
    if (lane >= d) x += y;
  }
  int ex = x - s;
  if (i0 < nb) bsum[i0] = ex;
  if (i1 < nb) bsum[i1] = ex + v0;
}

__global__ void scan3_kernel(int* __restrict__ off, const int* __restrict__ bsum, int nN) {
  int i = blockIdx.x * blockDim.x + threadIdx.x;
  if (i < nN) off[i] += bsum[i >> 10];
}

// permute (atomic-free): esrc[off[dst[e]] + rank[e]] = src[e]
__global__ void permute_kernel(const int* __restrict__ src, const int* __restrict__ dst,
                               const int* __restrict__ rank, const int* __restrict__ off,
                               int* __restrict__ esrc, int nE) {
  int t = blockIdx.x * blockDim.x + threadIdx.x;
  int e0 = t * 4;
  if (e0 + 3 < nE) {
    int4 d4 = *(const int4*)(dst + e0);
    int4 r4 = *(const int4*)(rank + e0);
    int4 s4 = *(const int4*)(src + e0);
    esrc[off[d4.x] + r4.x] = s4.x;
    esrc[off[d4.y] + r4.y] = s4.y;
    esrc[off[d4.z] + r4.z] = s4.z;
    esrc[off[d4.w] + r4.w] = s4.w;
  } else {
    for (int e = e0; e < nE; ++e) esrc[off[dst[e]] + rank[e]] = src[e];
  }
}

// ---------------- gather 1 (bf16, 128-dim): mean of src rows per node -------
// one wave per node; 8 edges in flight (4 lane-groups x 2 unroll), 16B/lane.
__global__ __launch_bounds__(256) void gather1_kernel(
    const ushort* __restrict__ feat, const int* __restrict__ esrc,
    const int* __restrict__ off, const int* __restrict__ deg,
    ushort* __restrict__ aggm, int nN) {
  const int w = (blockIdx.x * blockDim.x + threadIdx.x) >> 6;
  const int lane = threadIdx.x & 63;
  if (w >= nN) return;
  const int o = off[w];
  const int d = deg[w];
  const int g = lane >> 4;
  const int l = lane & 15;
  float acc[8] = {0.f, 0.f, 0.f, 0.f, 0.f, 0.f, 0.f, 0.f};
  int i = 0;
  for (; i + 8 <= d; i += 8) {
    int sA = esrc[o + i + g];
    int sB = esrc[o + i + 4 + g];
    uint4 vA = ((const uint4*)(feat + (size_t)sA * NF))[l];
    uint4 vB = ((const uint4*)(feat + (size_t)sB * NF))[l];
    acc[0] += b2f_lo(vA.x) + b2f_lo(vB.x); acc[1] += b2f_hi(vA.x) + b2f_hi(vB.x);
    acc[2] += b2f_lo(vA.y) + b2f_lo(vB.y); acc[3] += b2f_hi(vA.y) + b2f_hi(vB.y);
    acc[4] += b2f_lo(vA.z) + b2f_lo(vB.z); acc[5] += b2f_hi(vA.z) + b2f_hi(vB.z);
    acc[6] += b2f_lo(vA.w) + b2f_lo(vB.w); acc[7] += b2f_hi(vA.w) + b2f_hi(vB.w);
  }
  for (; i + 4 <= d; i += 4) {
    int s = esrc[o + i + g];
    uint4 v = ((const uint4*)(feat + (size_t)s * NF))[l];
    acc[0] += b2f_lo(v.x); acc[1] += b2f_hi(v.x);
    acc[2] += b2f_lo(v.y); acc[3] += b2f_hi(v.y);
    acc[4] += b2f_lo(v.z); acc[5] += b2f_hi(v.z);
    acc[6] += b2f_lo(v.w); acc[7] += b2f_hi(v.w);
  }
  if (i + g < d) {
    int s = esrc[o + i + g];
    uint4 v = ((const uint4*)(feat + (size_t)s * NF))[l];
    acc[0] += b2f_lo(v.x); acc[1] += b2f_hi(v.x);
    acc[2] += b2f_lo(v.y); acc[3] += b2f_hi(v.y);
    acc[4] += b2f_lo(v.z); acc[5] += b2f_hi(v.z);
    acc[6] += b2f_lo(v.w); acc[7] += b2f_hi(v.w);
  }
#pragma unroll
  for (int k = 0; k < 8; ++k) {
    acc[k] += __shfl_xor(acc[k], 16);
    acc[k] += __shfl_xor(acc[k], 32);
  }
  if (g == 0) {
    float inv = 1.0f / fmaxf((float)d, 1.0f);
    uint4 ov;
    ov.x = (uint)f2b(acc[0] * inv) | ((uint)f2b(acc[1] * inv) << 16);
    ov.y = (uint)f2b(acc[2] * inv) | ((uint)f2b(acc[3] * inv) << 16);
    ov.z = (uint)f2b(acc[4] * inv) | ((uint)f2b(acc[5] * inv) << 16);
    ov.w = (uint)f2b(acc[6] * inv) | ((uint)f2b(acc[7] * inv) << 16);
    ((uint4*)(aggm + (size_t)w * NF))[l] = ov;
  }
}

// ---------------- gather 2 (bf16 in, fp32 out, 64-dim rows) -----------------
// one wave per node; 8 edges in flight (4 lane-groups x 2 unroll), 8B/lane.
__global__ __launch_bounds__(256) void gather2_kernel(
    const ushort* __restrict__ z, const int* __restrict__ esrc,
    const int* __restrict__ off, const int* __restrict__ deg,
    float* __restrict__ aggz, int nN) {
  const int w = (blockIdx.x * blockDim.x + threadIdx.x) >> 6;
  const int lane = threadIdx.x & 63;
  if (w >= nN) return;
  const int o = off[w];
  const int d = deg[w];
  const int g = lane >> 4;
  const int l = lane & 15;
  float acc[4] = {0.f, 0.f, 0.f, 0.f};
  int i = 0;
  for (; i + 8 <= d; i += 8) {
    int sA = esrc[o + i + g];
    int sB = esrc[o + i + 4 + g];
    uint2 vA = ((const uint2*)(z + (size_t)sA * NC))[l];
    uint2 vB = ((const uint2*)(z + (size_t)sB * NC))[l];
    acc[0] += b2f_lo(vA.x) + b2f_lo(vB.x); acc[1] += b2f_hi(vA.x) + b2f_hi(vB.x);
    acc[2] += b2f_lo(vA.y) + b2f_lo(vB.y); acc[3] += b2f_hi(vA.y) + b2f_hi(vB.y);
  }
  for (; i + 4 <= d; i += 4) {
    int s = esrc[o + i + g];
    uint2 v = ((const uint2*)(z + (size_t)s * NC))[l];
    acc[0] += b2f_lo(v.x); acc[1] += b2f_hi(v.x);
    acc[2] += b2f_lo(v.y); acc[3] += b2f_hi(v.y);
  }
  if (i + g < d) {
    int s = esrc[o + i + g];
    uint2 v = ((const uint2*)(z + (size_t)s * NC))[l];
    acc[0] += b2f_lo(v.x); acc[1] += b2f_hi(v.x);
    acc[2] += b2f_lo(v.y); acc[3] += b2f_hi(v.y);
  }
#pragma unroll
  for (int k = 0; k < 4; ++k) {
    acc[k] += __shfl_xor(acc[k], 16);
    acc[k] += __shfl_xor(acc[k], 32);
  }
  if (g == 0) {
    float inv = 1.0f / fmaxf((float)d, 1.0f);
    ((float4*)(aggz + (size_t)w * NC))[l] =
        make_float4(acc[0] * inv, acc[1] * inv, acc[2] * inv, acc[3] * inv);
  }
}

// ---------------- layer 1 (MFMA): h = relu([mean||x] @ Wcat + b) ------------
__global__ __launch_bounds__(256) void layer1_mfma(
    const ushort* __restrict__ xb, const ushort* __restrict__ aggb,
    const ushort* __restrict__ Wp, const float* __restrict__ b1,
    ushort* __restrict__ hb, int nN) {
  const int t = threadIdx.x;
  const int wv = t >> 6;
  const int lane = t & 63;
  const int base = blockIdx.x * 64;
  __shared__ ushort As[64][264];  // 256 cols + 8 pad
  for (int i = t; i < 64 * 32; i += 256) {
    int r = i >> 5, cq = i & 31;
    int node = base + r;
    short8 v = {};
    if (node < nN) {
      const ushort* sp = (cq < 16) ? (aggb + (size_t)node * NF + cq * 8)
                                   : (xb + (size_t)node * NF + (cq - 16) * 8);
      v = *(const short8*)sp;
    }
    *(short8*)&As[r][cq * 8] = v;
  }
  __syncthreads();

  f32x4 acc[8] = {};
  const int arow = wv * 16 + (lane & 15);
  const int kq = (lane >> 4) * 8;
#pragma unroll
  for (int kt = 0; kt < 8; ++kt) {
    short8 af = *(const short8*)&As[arow][kt * 32 + kq];
#pragma unroll
    for (int nt = 0; nt < 8; ++nt) {
      short8 bf = *(const short8*)(Wp + ((size_t)(kt * 8 + nt) * 64 + lane) * 8);
      acc[nt] = __builtin_amdgcn_mfma_f32_16x16x32_bf16(af, bf, acc[nt], 0, 0, 0);
    }
  }
  const int quad = lane >> 4;
  const int cl = lane & 15;
#pragma unroll
  for (int nt = 0; nt < 8; ++nt) {
    float bj = b1[nt * 16 + cl];
#pragma unroll
    for (int r = 0; r < 4; ++r) {
      int node = base + wv * 16 + quad * 4 + r;
      if (node < nN) {
        float vv = fmaxf(acc[nt][r] + bj, 0.0f);
        hb[(size_t)node * NF + nt * 16 + cl] = f2b(vv);
      }
    }
  }
}

// ---------------- layer 2a (MFMA): z = h @ W2l^T (bf16 out, no bias) --------
__global__ __launch_bounds__(256) void layer2a_mfma(
    const ushort* __restrict__ hb, const ushort* __restrict__ Wp,
    ushort* __restrict__ z, int nN) {
  const int t = threadIdx.x;
  const int wv = t >> 6;
  const int lane = t & 63;
  const int base = blockIdx.x * 64;
  __shared__ ushort As[64][136];  // 128 cols + 8 pad
  for (int i = t; i < 64 * 16; i += 256) {
    int r = i >> 4, cq = i & 15;
    int node = base + r;
    short8 v = {};
    if (node < nN) v = *(const short8*)(hb + (size_t)node * NF + cq * 8);
    *(short8*)&As[r][cq * 8] = v;
  }
  __syncthreads();

  f32x4 acc[4] = {};
  const int arow = wv * 16 + (lane & 15);
  const int kq = (lane >> 4) * 8;
#pragma unroll
  for (int kt = 0; kt < 4; ++kt) {
    short8 af = *(const short8*)&As[arow][kt * 32 + kq];
#pragma unroll
    for (int nt = 0; nt < 4; ++nt) {
      short8 bf = *(const short8*)(Wp + ((size_t)(kt * 4 + nt) * 64 + lane) * 8);
      acc[nt] = __builtin_amdgcn_mfma_f32_16x16x32_bf16(af, bf, acc[nt], 0, 0, 0);
    }
  }
  const int quad = lane >> 4;
  const int cl = lane & 15;
#pragma unroll
  for (int nt = 0; nt < 4; ++nt) {
#pragma unroll
    for (int r = 0; r < 4; ++r) {
      int node = base + wv * 16 + quad * 4 + r;
      if (node < nN) z[(size_t)node * NC + nt * 16 + cl] = f2b(acc[nt][r]);
    }
  }
}

// ---------------- layer 2b (MFMA): out = logsoftmax(aggz + h@W2r^T + b) -----
__global__ __launch_bounds__(256) void layer2b_mfma(
    const ushort* __restrict__ hb, const float* __restrict__ aggz,
    const ushort* __restrict__ Wp, const float* __restrict__ b2,
    float* __restrict__ out, int nN) {
  const int t = threadIdx.x;
  const int wv = t >> 6;
  const int lane = t & 63;
  const int base = blockIdx.x * 64;
  __shared__ ushort As[64][136];
  for (int i = t; i < 64 * 16; i += 256) {
    int r = i >> 4, cq = i & 15;
    int node = base + r;
    short8 v = {};
    if (node < nN) v = *(const short8*)(hb + (size_t)node * NF + cq * 8);
    *(short8*)&As[r][cq * 8] = v;
  }
  __syncthreads();

  f32x4 acc[4] = {};
  const int arow = wv * 16 + (lane & 15);
  const int kq = (lane >> 4) * 8;
#pragma unroll
  for (int kt = 0; kt < 4; ++kt) {
    short8 af = *(const short8*)&As[arow][kt * 32 + kq];
#pragma unroll
    for (int nt = 0; nt < 4; ++nt) {
      short8 bf = *(const short8*)(Wp + ((size_t)(kt * 4 + nt) * 64 + lane) * 8);
      acc[nt] = __builtin_amdgcn_mfma_f32_16x16x32_bf16(af, bf, acc[nt], 0, 0, 0);
    }
  }
  const int quad = lane >> 4;
  const int cl = lane & 15;
  float bj[4];
#pragma unroll
  for (int nt = 0; nt < 4; ++nt) bj[nt] = b2[nt * 16 + cl];

#pragma unroll
  for (int r = 0; r < 4; ++r) {
    int node = base + wv * 16 + quad * 4 + r;
    int nvalid = (node < nN);
    const float* ap = aggz + (size_t)node * NC;
    float v0 = acc[0][r] + bj[0] + (nvalid ? ap[0 * 16 + cl] : 0.0f);
    float v1 = acc[1][r] + bj[1] + (nvalid ? ap[1 * 16 + cl] : 0.0f);
    float v2 = acc[2][r] + bj[2] + (nvalid ? ap[2 * 16 + cl] : 0.0f);
    float v3 = acc[3][r] + bj[3] + (nvalid ? ap[3 * 16 + cl] : 0.0f);
    float mx = fmaxf(fmaxf(v0, v1), fmaxf(v2, v3));
#pragma unroll
    for (int s = 1; s < 16; s <<= 1) mx = fmaxf(mx, __shfl_xor(mx, s));
    float sm = expf(v0 - mx) + expf(v1 - mx) + expf(v2 - mx) + expf(v3 - mx);
#pragma unroll
    for (int s = 1; s < 16; s <<= 1) sm += __shfl_xor(sm, s);
    float ls = mx + logf(sm);
    if (nvalid) {
      float* op = out + (size_t)node * NC;
      op[0 * 16 + cl] = v0 - ls;
      op[1 * 16 + cl] = v1 - ls;
      op[2 * 16 + cl] = v2 - ls;
      op[3 * 16 + cl] = v3 - ls;
    }
  }
}

extern "C" void kernel_launch(void* const* d_in, const int* in_sizes, int n_in,
                              void* d_out, int out_size, void* d_ws, size_t ws_size,
                              hipStream_t stream) {
  const float* x   = (const float*)d_in[0];
  const int*   ei  = (const int*)d_in[1];
  const float* W1l = (const float*)d_in[2];
  const float* b1l = (const float*)d_in[3];
  const float* W1r = (const float*)d_in[4];
  const float* W2l = (const float*)d_in[5];
  const float* b2l = (const float*)d_in[6];
  const float* W2r = (const float*)d_in[7];
  float* out = (float*)d_out;

  const int nN = in_sizes[0] / NF;  // 100000
  const int nE = in_sizes[1] / 2;   // 1600000
  const int* src = ei;
  const int* dst = ei + nE;

  char* p = (char*)d_ws;
  ushort* xb   = (ushort*)p; p += (size_t)nN * NF * 2;   // also reused as z (nN*NC*2 fits)
  ushort* hb   = (ushort*)p; p += (size_t)nN * NF * 2;
  ushort* aggb = (ushort*)p; p += (size_t)nN * NF * 2;   // also reused as aggz (fp32, nN*NC*4 == same bytes)
  ushort* Wp1  = (ushort*)p; p += 256 * 128 * 2;
  ushort* Wp2l = (ushort*)p; p += 128 * 64 * 2;
  ushort* Wp2r = (ushort*)p; p += 128 * 64 * 2;
  int* deg  = (int*)p; p += (size_t)nN * 4;
  int* off  = (int*)p; p += (size_t)nN * 4;
  int* bsum = (int*)p; p += 512;
  int* esrc = (int*)p; p += (size_t)nE * 4;
  int* rank = (int*)p; p += (size_t)nE * 4;

  ushort* z    = xb;            // alias: xb dead after layer1
  float*  aggz = (float*)aggb;  // alias: aggb dead after layer1

  const int nb1024 = (nN + 1023) / 1024;

  hipMemsetAsync(deg, 0, (size_t)nN * sizeof(int), stream);

  cast_kernel<<<(nN * NF / 4 + 255) / 256, 256, 0, stream>>>(x, xb, nN * NF / 4);
  pack1_kernel<<<(256 * 128 + 255) / 256, 256, 0, stream>>>(W1l, W1r, Wp1, 128);
  pack2_kernel<<<(2 * 8192 + 255) / 256, 256, 0, stream>>>(W2l, W2r, Wp2l, Wp2r);

  // --- build CSR by destination ---
  hist_kernel<<<(nE / 8 + 255) / 256, 256, 0, stream>>>(dst, deg, rank, nE);
  scan1_kernel<<<nb1024, 256, 0, stream>>>(deg, off, bsum, nN);
  scan2_kernel<<<1, 64, 0, stream>>>(bsum, nb1024);
  scan3_kernel<<<(nN + 255) / 256, 256, 0, stream>>>(off, bsum, nN);
  permute_kernel<<<(nE / 4 + 255) / 256, 256, 0, stream>>>(src, dst, rank, off, esrc, nE);

  // --- layer 1 ---
  gather1_kernel<<<(nN + 3) / 4, 256, 0, stream>>>(xb, esrc, off, deg, aggb, nN);
  layer1_mfma<<<(nN + 63) / 64, 256, 0, stream>>>(xb, aggb, Wp1, b1l, hb, nN);

  // --- layer 2 (projection-first: z = h@W2l, then mean, then +h@W2r) ---
  layer2a_mfma<<<(nN + 63) / 64, 256, 0, stream>>>(hb, Wp2l, z, nN);
  gather2_kernel<<<(nN + 3) / 4, 256, 0, stream>>>(z, esrc, off, deg, aggz, nN);
  layer2b_mfma<<<(nN + 63) / 64, 256, 0, stream>>>(hb, aggz, Wp2r, b2l, out, nN);
}

// Round 7
// 383.939 us; speedup vs baseline: 15.1611x; 1.0202x over previous
//
#include <hip/hip_runtime.h>

#define NF 128   // FEATURE == HIDDEN
#define NC 64    // CLASSES

typedef short short8 __attribute__((ext_vector_type(8)));
typedef unsigned short ushort;
typedef float f32x4 __attribute__((ext_vector_type(4)));
typedef unsigned int uint;

__device__ __forceinline__ ushort f2b(float x) {  // RNE float->bf16
  unsigned u = __builtin_bit_cast(unsigned, x);
  u += 0x7fffu + ((u >> 16) & 1u);
  return (ushort)(u >> 16);
}
__device__ __forceinline__ float b2f_lo(unsigned v) {
  return __builtin_bit_cast(float, v << 16);
}
__device__ __forceinline__ float b2f_hi(unsigned v) {
  return __builtin_bit_cast(float, v & 0xffff0000u);
}

// ---------------- fused prep: cast x->bf16, pack W1, pack W2l/W2r -----------
__global__ void prep_kernel(const float* __restrict__ x, ushort* __restrict__ xb, int n4,
                            int nb_cast,
                            const float* __restrict__ W1l, const float* __restrict__ W1r,
                            ushort* __restrict__ Wp1,
                            const float* __restrict__ W2l, const float* __restrict__ W2r,
                            ushort* __restrict__ Wp2l, ushort* __restrict__ Wp2r) {
  int b = blockIdx.x;
  if (b < nb_cast) {
    int i = b * 256 + threadIdx.x;
    if (i >= n4) return;
    float4 v = ((const float4*)x)[i];
    ushort4 o;
    o.x = f2b(v.x); o.y = f2b(v.y); o.z = f2b(v.z); o.w = f2b(v.w);
    ((ushort4*)xb)[i] = o;
  } else if (b < nb_cast + 128) {
    // pack [W1l||W1r] (K=256, N=128) -> MFMA B-frag
    int tid = (b - nb_cast) * 256 + threadIdx.x;  // 0..32767
    int j = tid & 7;
    int lane = (tid >> 3) & 63;
    int tile = tid >> 9;
    int nt = tile & 7, kt = tile >> 3;  // NT = 8
    int k = kt * 32 + ((lane >> 4) << 3) + j;
    int n = nt * 16 + (lane & 15);
    float v = (k < 128) ? W1l[n * 128 + k] : W1r[n * 128 + (k - 128)];
    Wp1[tid] = f2b(v);
  } else {
    // pack W2l and W2r (K=128, N=64) -> MFMA B-frag
    int tid0 = (b - nb_cast - 128) * 256 + threadIdx.x;  // 0..16383
    int which = tid0 >> 13;
    int tid = tid0 & 8191;
    int j = tid & 7;
    int lane = (tid >> 3) & 63;
    int tile = tid >> 9;  // 0..15
    int nt = tile & 3, kt = tile >> 2;
    int k = kt * 32 + ((lane >> 4) << 3) + j;
    int n = nt * 16 + (lane & 15);
    const float* W = which ? W2r : W2l;
    ushort* Wp = which ? Wp2r : Wp2l;
    Wp[tid] = f2b(W[n * 128 + k]);
  }
}

// ---------------- CSR build: padded histogram (1 counter / cacheline) -------
__global__ void hist_kernel(const int* __restrict__ dst, int* __restrict__ degP,
                            int* __restrict__ rank, int nE) {
  int t = blockIdx.x * blockDim.x + threadIdx.x;
  int e0 = t * 4;
  if (e0 + 3 < nE) {
    int4 d4 = *(const int4*)(dst + e0);
    int4 r4;
    r4.x = atomicAdd(&degP[(size_t)d4.x << 4], 1);
    r4.y = atomicAdd(&degP[(size_t)d4.y << 4], 1);
    r4.z = atomicAdd(&degP[(size_t)d4.z << 4], 1);
    r4.w = atomicAdd(&degP[(size_t)d4.w << 4], 1);
    *(int4*)(rank + e0) = r4;
  } else {
    for (int e = e0; e < nE; ++e) rank[e] = atomicAdd(&degP[(size_t)dst[e] << 4], 1);
  }
}

// scan phase 1: read strided degP, write exclusive scan -> off, compact deg, bsum
__global__ __launch_bounds__(256) void scan1_kernel(const int* __restrict__ degP,
                                                    int* __restrict__ off,
                                                    int* __restrict__ deg,
                                                    int* __restrict__ bsum, int nN) {
  const int t = threadIdx.x;
  const int base = blockIdx.x * 1024 + t * 4;
  int v[4];
  int tsum = 0;
#pragma unroll
  for (int k = 0; k < 4; ++k) {
    v[k] = (base + k < nN) ? degP[(size_t)(base + k) << 4] : 0;
    tsum += v[k];
  }
  int lane = t & 63, wid = t >> 6;
  int x = tsum;
#pragma unroll
  for (int d = 1; d < 64; d <<= 1) {
    int y = __shfl_up(x, d);
    if (lane >= d) x += y;
  }
  __shared__ int wsum[4];
  if (lane == 63) wsum[wid] = x;
  __syncthreads();
  int wbase = 0;
  for (int w = 0; w < wid; ++w) wbase += wsum[w];
  int run = wbase + x - tsum;
#pragma unroll
  for (int k = 0; k < 4; ++k) {
    if (base + k < nN) {
      off[base + k] = run;
      deg[base + k] = v[k];
    }
    run += v[k];
  }
  if (t == 0) bsum[blockIdx.x] = wsum[0] + wsum[1] + wsum[2] + wsum[3];
}

// wave-parallel exclusive scan of block sums (nb <= 128), one 64-lane wave
__global__ void scan2_kernel(int* __restrict__ bsum, int nb) {
  int lane = threadIdx.x;
  int i0 = 2 * lane, i1 = 2 * lane + 1;
  int v0 = (i0 < nb) ? bsum[i0] : 0;
  int v1 = (i1 < nb) ? bsum[i1] : 0;
  int s = v0 + v1;
  int x = s;
#pragma unroll
  for (int d = 1; d < 64; d <<= 1) {
    int y = __shfl_up(x, d);
    if (lane >= d) x += y;
  }
  int ex = x - s;
  if (i0 < nb) bsum[i0] = ex;
  if (i1 < nb) bsum[i1] = ex + v0;
}

__global__ void scan3_kernel(int* __restrict__ off, const int* __restrict__ bsum, int nN) {
  int i = blockIdx.x * blockDim.x + threadIdx.x;
  if (i < nN) off[i] += bsum[i >> 10];
}

// permute (atomic-free): esrc[off[dst[e]] + rank[e]] = src[e]
__global__ void permute_kernel(const int* __restrict__ src, const int* __restrict__ dst,
                               const int* __restrict__ rank, const int* __restrict__ off,
                               int* __restrict__ esrc, int nE) {
  int t = blockIdx.x * blockDim.x + threadIdx.x;
  int e0 = t * 4;
  if (e0 + 3 < nE) {
    int4 d4 = *(const int4*)(dst + e0);
    int4 r4 = *(const int4*)(rank + e0);
    int4 s4 = *(const int4*)(src + e0);
    esrc[off[d4.x] + r4.x] = s4.x;
    esrc[off[d4.y] + r4.y] = s4.y;
    esrc[off[d4.z] + r4.z] = s4.z;
    esrc[off[d4.w] + r4.w] = s4.w;
  } else {
    for (int e = e0; e < nE; ++e) esrc[off[dst[e]] + rank[e]] = src[e];
  }
}

// ---------------- gather 1 (bf16, 128-dim): mean of src rows per node -------
__global__ __launch_bounds__(256) void gather1_kernel(
    const ushort* __restrict__ feat, const int* __restrict__ esrc,
    const int* __restrict__ off, const int* __restrict__ deg,
    ushort* __restrict__ aggm, int nN) {
  const int w = (blockIdx.x * blockDim.x + threadIdx.x) >> 6;
  const int lane = threadIdx.x & 63;
  if (w >= nN) return;
  const int o = off[w];
  const int d = deg[w];
  const int g = lane >> 4;
  const int l = lane & 15;
  float acc[8] = {0.f, 0.f, 0.f, 0.f, 0.f, 0.f, 0.f, 0.f};
  int i = 0;
  for (; i + 8 <= d; i += 8) {
    int sA = esrc[o + i + g];
    int sB = esrc[o + i + 4 + g];
    uint4 vA = ((const uint4*)(feat + (size_t)sA * NF))[l];
    uint4 vB = ((const uint4*)(feat + (size_t)sB * NF))[l];
    acc[0] += b2f_lo(vA.x) + b2f_lo(vB.x); acc[1] += b2f_hi(vA.x) + b2f_hi(vB.x);
    acc[2] += b2f_lo(vA.y) + b2f_lo(vB.y); acc[3] += b2f_hi(vA.y) + b2f_hi(vB.y);
    acc[4] += b2f_lo(vA.z) + b2f_lo(vB.z); acc[5] += b2f_hi(vA.z) + b2f_hi(vB.z);
    acc[6] += b2f_lo(vA.w) + b2f_lo(vB.w); acc[7] += b2f_hi(vA.w) + b2f_hi(vB.w);
  }
  for (; i + 4 <= d; i += 4) {
    int s = esrc[o + i + g];
    uint4 v = ((const uint4*)(feat + (size_t)s * NF))[l];
    acc[0] += b2f_lo(v.x); acc[1] += b2f_hi(v.x);
    acc[2] += b2f_lo(v.y); acc[3] += b2f_hi(v.y);
    acc[4] += b2f_lo(v.z); acc[5] += b2f_hi(v.z);
    acc[6] += b2f_lo(v.w); acc[7] += b2f_hi(v.w);
  }
  if (i + g < d) {
    int s = esrc[o + i + g];
    uint4 v = ((const uint4*)(feat + (size_t)s * NF))[l];
    acc[0] += b2f_lo(v.x); acc[1] += b2f_hi(v.x);
    acc[2] += b2f_lo(v.y); acc[3] += b2f_hi(v.y);
    acc[4] += b2f_lo(v.z); acc[5] += b2f_hi(v.z);
    acc[6] += b2f_lo(v.w); acc[7] += b2f_hi(v.w);
  }
#pragma unroll
  for (int k = 0; k < 8; ++k) {
    acc[k] += __shfl_xor(acc[k], 16);
    acc[k] += __shfl_xor(acc[k], 32);
  }
  if (g == 0) {
    float inv = 1.0f / fmaxf((float)d, 1.0f);
    uint4 ov;
    ov.x = (uint)f2b(acc[0] * inv) | ((uint)f2b(acc[1] * inv) << 16);
    ov.y = (uint)f2b(acc[2] * inv) | ((uint)f2b(acc[3] * inv) << 16);
    ov.z = (uint)f2b(acc[4] * inv) | ((uint)f2b(acc[5] * inv) << 16);
    ov.w = (uint)f2b(acc[6] * inv) | ((uint)f2b(acc[7] * inv) << 16);
    ((uint4*)(aggm + (size_t)w * NF))[l] = ov;
  }
}

// ---------------- gather 2 (bf16 in, fp32 out, 64-dim rows) -----------------
__global__ __launch_bounds__(256) void gather2_kernel(
    const ushort* __restrict__ z, const int* __restrict__ esrc,
    const int* __restrict__ off, const int* __restrict__ deg,
    float* __restrict__ aggz, int nN) {
  const int w = (blockIdx.x * blockDim.x + threadIdx.x) >> 6;
  const int lane = threadIdx.x & 63;
  if (w >= nN) return;
  const int o = off[w];
  const int d = deg[w];
  const int g = lane >> 4;
  const int l = lane & 15;
  float acc[4] = {0.f, 0.f, 0.f, 0.f};
  int i = 0;
  for (; i + 8 <= d; i += 8) {
    int sA = esrc[o + i + g];
    int sB = esrc[o + i + 4 + g];
    uint2 vA = ((const uint2*)(z + (size_t)sA * NC))[l];
    uint2 vB = ((const uint2*)(z + (size_t)sB * NC))[l];
    acc[0] += b2f_lo(vA.x) + b2f_lo(vB.x); acc[1] += b2f_hi(vA.x) + b2f_hi(vB.x);
    acc[2] += b2f_lo(vA.y) + b2f_lo(vB.y); acc[3] += b2f_hi(vA.y) + b2f_hi(vB.y);
  }
  for (; i + 4 <= d; i += 4) {
    int s = esrc[o + i + g];
    uint2 v = ((const uint2*)(z + (size_t)s * NC))[l];
    acc[0] += b2f_lo(v.x); acc[1] += b2f_hi(v.x);
    acc[2] += b2f_lo(v.y); acc[3] += b2f_hi(v.y);
  }
  if (i + g < d) {
    int s = esrc[o + i + g];
    uint2 v = ((const uint2*)(z + (size_t)s * NC))[l];
    acc[0] += b2f_lo(v.x); acc[1] += b2f_hi(v.x);
    acc[2] += b2f_lo(v.y); acc[3] += b2f_hi(v.y);
  }
#pragma unroll
  for (int k = 0; k < 4; ++k) {
    acc[k] += __shfl_xor(acc[k], 16);
    acc[k] += __shfl_xor(acc[k], 32);
  }
  if (g == 0) {
    float inv = 1.0f / fmaxf((float)d, 1.0f);
    ((float4*)(aggz + (size_t)w * NC))[l] =
        make_float4(acc[0] * inv, acc[1] * inv, acc[2] * inv, acc[3] * inv);
  }
}

// ---------------- layer 1 (MFMA): h = relu([mean||x] @ Wcat + b) ------------
__global__ __launch_bounds__(256) void layer1_mfma(
    const ushort* __restrict__ xb, const ushort* __restrict__ aggb,
    const ushort* __restrict__ Wp, const float* __restrict__ b1,
    ushort* __restrict__ hb, int nN) {
  const int t = threadIdx.x;
  const int wv = t >> 6;
  const int lane = t & 63;
  const int base = blockIdx.x * 64;
  __shared__ ushort As[64][264];  // 256 cols + 8 pad
  for (int i = t; i < 64 * 32; i += 256) {
    int r = i >> 5, cq = i & 31;
    int node = base + r;
    short8 v = {};
    if (node < nN) {
      const ushort* sp = (cq < 16) ? (aggb + (size_t)node * NF + cq * 8)
                                   : (xb + (size_t)node * NF + (cq - 16) * 8);
      v = *(const short8*)sp;
    }
    *(short8*)&As[r][cq * 8] = v;
  }
  __syncthreads();

  f32x4 acc[8] = {};
  const int arow = wv * 16 + (lane & 15);
  const int kq = (lane >> 4) * 8;
#pragma unroll
  for (int kt = 0; kt < 8; ++kt) {
    short8 af = *(const short8*)&As[arow][kt * 32 + kq];
#pragma unroll
    for (int nt = 0; nt < 8; ++nt) {
      short8 bf = *(const short8*)(Wp + ((size_t)(kt * 8 + nt) * 64 + lane) * 8);
      acc[nt] = __builtin_amdgcn_mfma_f32_16x16x32_bf16(af, bf, acc[nt], 0, 0, 0);
    }
  }
  const int quad = lane >> 4;
  const int cl = lane & 15;
#pragma unroll
  for (int nt = 0; nt < 8; ++nt) {
    float bj = b1[nt * 16 + cl];
#pragma unroll
    for (int r = 0; r < 4; ++r) {
      int node = base + wv * 16 + quad * 4 + r;
      if (node < nN) {
        float vv = fmaxf(acc[nt][r] + bj, 0.0f);
        hb[(size_t)node * NF + nt * 16 + cl] = f2b(vv);
      }
    }
  }
}

// ---------------- layer 2a (MFMA): z = h @ W2l^T (bf16 out, no bias) --------
__global__ __launch_bounds__(256) void layer2a_mfma(
    const ushort* __restrict__ hb, const ushort* __restrict__ Wp,
    ushort* __restrict__ z, int nN) {
  const int t = threadIdx.x;
  const int wv = t >> 6;
  const int lane = t & 63;
  const int base = blockIdx.x * 64;
  __shared__ ushort As[64][136];  // 128 cols + 8 pad
  for (int i = t; i < 64 * 16; i += 256) {
    int r = i >> 4, cq = i & 15;
    int node = base + r;
    short8 v = {};
    if (node < nN) v = *(const short8*)(hb + (size_t)node * NF + cq * 8);
    *(short8*)&As[r][cq * 8] = v;
  }
  __syncthreads();

  f32x4 acc[4] = {};
  const int arow = wv * 16 + (lane & 15);
  const int kq = (lane >> 4) * 8;
#pragma unroll
  for (int kt = 0; kt < 4; ++kt) {
    short8 af = *(const short8*)&As[arow][kt * 32 + kq];
#pragma unroll
    for (int nt = 0; nt < 4; ++nt) {
      short8 bf = *(const short8*)(Wp + ((size_t)(kt * 4 + nt) * 64 + lane) * 8);
      acc[nt] = __builtin_amdgcn_mfma_f32_16x16x32_bf16(af, bf, acc[nt], 0, 0, 0);
    }
  }
  const int quad = lane >> 4;
  const int cl = lane & 15;
#pragma unroll
  for (int nt = 0; nt < 4; ++nt) {
#pragma unroll
    for (int r = 0; r < 4; ++r) {
      int node = base + wv * 16 + quad * 4 + r;
      if (node < nN) z[(size_t)node * NC + nt * 16 + cl] = f2b(acc[nt][r]);
    }
  }
}

// ---------------- layer 2b (MFMA): out = logsoftmax(aggz + h@W2r^T + b) -----
__global__ __launch_bounds__(256) void layer2b_mfma(
    const ushort* __restrict__ hb, const float* __restrict__ aggz,
    const ushort* __restrict__ Wp, const float* __restrict__ b2,
    float* __restrict__ out, int nN) {
  const int t = threadIdx.x;
  const int wv = t >> 6;
  const int lane = t & 63;
  const int base = blockIdx.x * 64;
  __shared__ ushort As[64][136];
  for (int i = t; i < 64 * 16; i += 256) {
    int r = i >> 4, cq = i & 15;
    int node = base + r;
    short8 v = {};
    if (node < nN) v = *(const short8*)(hb + (size_t)node * NF + cq * 8);
    *(short8*)&As[r][cq * 8] = v;
  }
  __syncthreads();

  f32x4 acc[4] = {};
  const int arow = wv * 16 + (lane & 15);
  const int kq = (lane >> 4) * 8;
#pragma unroll
  for (int kt = 0; kt < 4; ++kt) {
    short8 af = *(const short8*)&As[arow][kt * 32 + kq];
#pragma unroll
    for (int nt = 0; nt < 4; ++nt) {
      short8 bf = *(const short8*)(Wp + ((size_t)(kt * 4 + nt) * 64 + lane) * 8);
      acc[nt] = __builtin_amdgcn_mfma_f32_16x16x32_bf16(af, bf, acc[nt], 0, 0, 0);
    }
  }
  const int quad = lane >> 4;
  const int cl = lane & 15;
  float bj[4];
#pragma unroll
  for (int nt = 0; nt < 4; ++nt) bj[nt] = b2[nt * 16 + cl];

#pragma unroll
  for (int r = 0; r < 4; ++r) {
    int node = base + wv * 16 + quad * 4 + r;
    int nvalid = (node < nN);
    const float* ap = aggz + (size_t)node * NC;
    float v0 = acc[0][r] + bj[0] + (nvalid ? ap[0 * 16 + cl] : 0.0f);
    float v1 = acc[1][r] + bj[1] + (nvalid ? ap[1 * 16 + cl] : 0.0f);
    float v2 = acc[2][r] + bj[2] + (nvalid ? ap[2 * 16 + cl] : 0.0f);
    float v3 = acc[3][r] + bj[3] + (nvalid ? ap[3 * 16 + cl] : 0.0f);
    float mx = fmaxf(fmaxf(v0, v1), fmaxf(v2, v3));
#pragma unroll
    for (int s = 1; s < 16; s <<= 1) mx = fmaxf(mx, __shfl_xor(mx, s));
    float sm = expf(v0 - mx) + expf(v1 - mx) + expf(v2 - mx) + expf(v3 - mx);
#pragma unroll
    for (int s = 1; s < 16; s <<= 1) sm += __shfl_xor(sm, s);
    float ls = mx + logf(sm);
    if (nvalid) {
      float* op = out + (size_t)node * NC;
      op[0 * 16 + cl] = v0 - ls;
      op[1 * 16 + cl] = v1 - ls;
      op[2 * 16 + cl] = v2 - ls;
      op[3 * 16 + cl] = v3 - ls;
    }
  }
}

extern "C" void kernel_launch(void* const* d_in, const int* in_sizes, int n_in,
                              void* d_out, int out_size, void* d_ws, size_t ws_size,
                              hipStream_t stream) {
  const float* x   = (const float*)d_in[0];
  const int*   ei  = (const int*)d_in[1];
  const float* W1l = (const float*)d_in[2];
  const float* b1l = (const float*)d_in[3];
  const float* W1r = (const float*)d_in[4];
  const float* W2l = (const float*)d_in[5];
  const float* b2l = (const float*)d_in[6];
  const float* W2r = (const float*)d_in[7];
  float* out = (float*)d_out;

  const int nN = in_sizes[0] / NF;  // 100000
  const int nE = in_sizes[1] / 2;   // 1600000
  const int* src = ei;
  const int* dst = ei + nE;

  char* p = (char*)d_ws;
  ushort* xb   = (ushort*)p; p += (size_t)nN * NF * 2;   // reused as z after layer1
  ushort* hb   = (ushort*)p; p += (size_t)nN * NF * 2;
  ushort* aggb = (ushort*)p; p += (size_t)nN * NF * 2;   // reused as aggz (fp32, same bytes)
  ushort* Wp1  = (ushort*)p; p += 256 * 128 * 2;
  ushort* Wp2l = (ushort*)p; p += 128 * 64 * 2;
  ushort* Wp2r = (ushort*)p; p += 128 * 64 * 2;
  int* degP = (int*)p; p += (size_t)nN * 16 * 4;  // 1 counter per 64B line
  int* deg  = (int*)p; p += (size_t)nN * 4;
  int* off  = (int*)p; p += (size_t)nN * 4;
  int* bsum = (int*)p; p += 512;
  int* esrc = (int*)p; p += (size_t)nE * 4;
  int* rank = (int*)p; p += (size_t)nE * 4;

  ushort* z    = xb;            // alias: xb dead after layer1
  float*  aggz = (float*)aggb;  // alias: aggb dead after layer1

  const int nb1024 = (nN + 1023) / 1024;
  const int n4 = nN * NF / 4;
  const int nb_cast = (n4 + 255) / 256;

  hipMemsetAsync(degP, 0, (size_t)nN * 16 * sizeof(int), stream);

  prep_kernel<<<nb_cast + 128 + 64, 256, 0, stream>>>(x, xb, n4, nb_cast,
                                                      W1l, W1r, Wp1,
                                                      W2l, W2r, Wp2l, Wp2r);

  // --- build CSR by destination ---
  hist_kernel<<<(nE / 4 + 255) / 256, 256, 0, stream>>>(dst, degP, rank, nE);
  scan1_kernel<<<nb1024, 256, 0, stream>>>(degP, off, deg, bsum, nN);
  scan2_kernel<<<1, 64, 0, stream>>>(bsum, nb1024);
  scan3_kernel<<<(nN + 255) / 256, 256, 0, stream>>>(off, bsum, nN);
  permute_kernel<<<(nE / 4 + 255) / 256, 256, 0, stream>>>(src, dst, rank, off, esrc, nE);

  // --- layer 1 ---
  gather1_kernel<<<(nN + 3) / 4, 256, 0, stream>>>(xb, esrc, off, deg, aggb, nN);
  layer1_mfma<<<(nN + 63) / 64, 256, 0, stream>>>(xb, aggb, Wp1, b1l, hb, nN);

  // --- layer 2 (projection-first: z = h@W2l, then mean, then +h@W2r) ---
  layer2a_mfma<<<(nN + 63) / 64, 256, 0, stream>>>(hb, Wp2l, z, nN);
  gather2_kernel<<<(nN + 3) / 4, 256, 0, stream>>>(z, esrc, off, deg, aggz, nN);
  layer2b_mfma<<<(nN + 63) / 64, 256, 0, stream>>>(hb, aggz, Wp2r, b2l, out, nN);
}

// Round 8
// 337.383 us; speedup vs baseline: 17.2532x; 1.1380x over previous
//
#include <hip/hip_runtime.h>

#define NF 128   // FEATURE == HIDDEN
#define NC 64    // CLASSES
#define NBA 640  // pass-A blocks
#define NBKT 196 // ceil(100000/512) coarse buckets

typedef short short8 __attribute__((ext_vector_type(8)));
typedef unsigned short ushort;
typedef float f32x4 __attribute__((ext_vector_type(4)));
typedef unsigned int uint;

__device__ __forceinline__ ushort f2b(float x) {  // RNE float->bf16
  unsigned u = __builtin_bit_cast(unsigned, x);
  u += 0x7fffu + ((u >> 16) & 1u);
  return (ushort)(u >> 16);
}
__device__ __forceinline__ float b2f_lo(unsigned v) {
  return __builtin_bit_cast(float, v << 16);
}
__device__ __forceinline__ float b2f_hi(unsigned v) {
  return __builtin_bit_cast(float, v & 0xffff0000u);
}

// ---------------- fused prep: cast x->bf16, pack W1, pack W2l/W2r -----------
__global__ void prep_kernel(const float* __restrict__ x, ushort* __restrict__ xb, int n4,
                            int nb_cast,
                            const float* __restrict__ W1l, const float* __restrict__ W1r,
                            ushort* __restrict__ Wp1,
                            const float* __restrict__ W2l, const float* __restrict__ W2r,
                            ushort* __restrict__ Wp2l, ushort* __restrict__ Wp2r) {
  int b = blockIdx.x;
  if (b < nb_cast) {
    int i = b * 256 + threadIdx.x;
    if (i >= n4) return;
    float4 v = ((const float4*)x)[i];
    ushort4 o;
    o.x = f2b(v.x); o.y = f2b(v.y); o.z = f2b(v.z); o.w = f2b(v.w);
    ((ushort4*)xb)[i] = o;
  } else if (b < nb_cast + 128) {
    int tid = (b - nb_cast) * 256 + threadIdx.x;  // 0..32767
    int j = tid & 7;
    int lane = (tid >> 3) & 63;
    int tile = tid >> 9;
    int nt = tile & 7, kt = tile >> 3;
    int k = kt * 32 + ((lane >> 4) << 3) + j;
    int n = nt * 16 + (lane & 15);
    float v = (k < 128) ? W1l[n * 128 + k] : W1r[n * 128 + (k - 128)];
    Wp1[tid] = f2b(v);
  } else {
    int tid0 = (b - nb_cast - 128) * 256 + threadIdx.x;  // 0..16383
    int which = tid0 >> 13;
    int tid = tid0 & 8191;
    int j = tid & 7;
    int lane = (tid >> 3) & 63;
    int tile = tid >> 9;
    int nt = tile & 3, kt = tile >> 2;
    int k = kt * 32 + ((lane >> 4) << 3) + j;
    int n = nt * 16 + (lane & 15);
    const float* W = which ? W2r : W2l;
    ushort* Wp = which ? Wp2r : Wp2l;
    Wp[tid] = f2b(W[n * 128 + k]);
  }
}

// ---------------- CSR build pass A1: per-block coarse histogram -------------
__global__ __launch_bounds__(256) void bhistA_kernel(const int* __restrict__ dst,
                                                     int* __restrict__ cntA,
                                                     int nE, int epb) {
  __shared__ int lh[NBKT];
  const int t = threadIdx.x;
  for (int i = t; i < NBKT; i += 256) lh[i] = 0;
  __syncthreads();
  int s0 = blockIdx.x * epb, s1 = min(nE, s0 + epb);
  for (int e = s0 + t; e < s1; e += 256) atomicAdd(&lh[dst[e] >> 9], 1);
  __syncthreads();
  for (int i = t; i < NBKT; i += 256)
    cntA[(size_t)i * NBA + blockIdx.x] = lh[i];
}

// ---------------- generic exclusive scan (3 kernels) over L <= 131072 -------
__global__ __launch_bounds__(256) void scanL1_kernel(const int* __restrict__ in,
                                                     int* __restrict__ out,
                                                     int* __restrict__ bsum, int L) {
  const int t = threadIdx.x;
  const int base = blockIdx.x * 1024 + t * 4;
  int v[4];
  int tsum = 0;
#pragma unroll
  for (int k = 0; k < 4; ++k) {
    v[k] = (base + k < L) ? in[base + k] : 0;
    tsum += v[k];
  }
  int lane = t & 63, wid = t >> 6;
  int x = tsum;
#pragma unroll
  for (int d = 1; d < 64; d <<= 1) {
    int y = __shfl_up(x, d);
    if (lane >= d) x += y;
  }
  __shared__ int wsum[4];
  if (lane == 63) wsum[wid] = x;
  __syncthreads();
  int wbase = 0;
  for (int w = 0; w < wid; ++w) wbase += wsum[w];
  int run = wbase + x - tsum;
#pragma unroll
  for (int k = 0; k < 4; ++k) {
    if (base + k < L) out[base + k] = run;
    run += v[k];
  }
  if (t == 0) bsum[blockIdx.x] = wsum[0] + wsum[1] + wsum[2] + wsum[3];
}

__global__ void scanL2_kernel(int* __restrict__ bsum, int nb) {
  int lane = threadIdx.x;
  int i0 = 2 * lane, i1 = 2 * lane + 1;
  int v0 = (i0 < nb) ? bsum[i0] : 0;
  int v1 = (i1 < nb) ? bsum[i1] : 0;
  int s = v0 + v1;
  int x = s;
#pragma unroll
  for (int d = 1; d < 64; d <<= 1) {
    int y = __shfl_up(x, d);
    if (lane >= d) x += y;
  }
  int ex = x - s;
  if (i0 < nb) bsum[i0] = ex;
  if (i1 < nb) bsum[i1] = ex + v0;
}

__global__ void scanL3_kernel(int* __restrict__ out, const int* __restrict__ bsum, int L) {
  int i = blockIdx.x * blockDim.x + threadIdx.x;
  if (i < L) out[i] += bsum[i >> 10];
}

// ---------------- CSR build pass A3: scatter into coarse buckets ------------
__global__ __launch_bounds__(256) void bscatA_kernel(const int* __restrict__ src,
                                                     const int* __restrict__ dst,
                                                     const int* __restrict__ cntS,
                                                     int2* __restrict__ tmp,
                                                     int nE, int epb) {
  __shared__ int base[NBKT];
  __shared__ int cur[NBKT];
  const int t = threadIdx.x;
  for (int i = t; i < NBKT; i += 256) {
    base[i] = cntS[(size_t)i * NBA + blockIdx.x];
    cur[i] = 0;
  }
  __syncthreads();
  int s0 = blockIdx.x * epb, s1 = min(nE, s0 + epb);
  for (int e = s0 + t; e < s1; e += 256) {
    int d = dst[e];
    int s = src[e];
    int b = d >> 9;
    int r = atomicAdd(&cur[b], 1);
    tmp[base[b] + r] = make_int2(d, s);
  }
}

// ---------------- CSR build pass B: per-bucket node sort + deg/off ----------
__global__ __launch_bounds__(256) void bsortB_kernel(const int2* __restrict__ tmp,
                                                     const int* __restrict__ cntS,
                                                     int* __restrict__ esrc,
                                                     int* __restrict__ deg,
                                                     int* __restrict__ off,
                                                     int nN, int nE) {
  const int bkt = blockIdx.x;
  const int t = threadIdx.x;
  __shared__ int lh[512];
  __shared__ int cur[512];
  __shared__ int wsum[4];
  const int start = cntS[(size_t)bkt * NBA];
  const int end = (bkt + 1 < NBKT) ? cntS[(size_t)(bkt + 1) * NBA] : nE;
  lh[t] = 0;
  lh[t + 256] = 0;
  __syncthreads();
  for (int i = start + t; i < end; i += 256) {
    int2 e = tmp[i];
    atomicAdd(&lh[e.x & 511], 1);
  }
  __syncthreads();
  // block exclusive scan of 512 bins (2/thread)
  int v0 = lh[2 * t], v1 = lh[2 * t + 1];
  int ts = v0 + v1;
  int lane = t & 63, wid = t >> 6;
  int x = ts;
#pragma unroll
  for (int d = 1; d < 64; d <<= 1) {
    int y = __shfl_up(x, d);
    if (lane >= d) x += y;
  }
  if (lane == 63) wsum[wid] = x;
  __syncthreads();
  int wb = 0;
  for (int w = 0; w < wid; ++w) wb += wsum[w];
  int ex = wb + x - ts;
  cur[2 * t] = ex;
  cur[2 * t + 1] = ex + v0;
  int n0 = (bkt << 9) + 2 * t, n1 = n0 + 1;
  if (n0 < nN) { off[n0] = start + ex;      deg[n0] = v0; }
  if (n1 < nN) { off[n1] = start + ex + v0; deg[n1] = v1; }
  __syncthreads();
  for (int i = start + t; i < end; i += 256) {
    int2 e = tmp[i];
    int r = atomicAdd(&cur[e.x & 511], 1);
    esrc[start + r] = e.y;
  }
}

// ---------------- gather 1 (bf16, 128-dim): mean of src rows per node -------
__global__ __launch_bounds__(256) void gather1_kernel(
    const ushort* __restrict__ feat, const int* __restrict__ esrc,
    const int* __restrict__ off, const int* __restrict__ deg,
    ushort* __restrict__ aggm, int nN) {
  const int w = (blockIdx.x * blockDim.x + threadIdx.x) >> 6;
  const int lane = threadIdx.x & 63;
  if (w >= nN) return;
  const int o = off[w];
  const int d = deg[w];
  const int g = lane >> 4;
  const int l = lane & 15;
  float acc[8] = {0.f, 0.f, 0.f, 0.f, 0.f, 0.f, 0.f, 0.f};
  int i = 0;
  for (; i + 8 <= d; i += 8) {
    int sA = esrc[o + i + g];
    int sB = esrc[o + i + 4 + g];
    uint4 vA = ((const uint4*)(feat + (size_t)sA * NF))[l];
    uint4 vB = ((const uint4*)(feat + (size_t)sB * NF))[l];
    acc[0] += b2f_lo(vA.x) + b2f_lo(vB.x); acc[1] += b2f_hi(vA.x) + b2f_hi(vB.x);
    acc[2] += b2f_lo(vA.y) + b2f_lo(vB.y); acc[3] += b2f_hi(vA.y) + b2f_hi(vB.y);
    acc[4] += b2f_lo(vA.z) + b2f_lo(vB.z); acc[5] += b2f_hi(vA.z) + b2f_hi(vB.z);
    acc[6] += b2f_lo(vA.w) + b2f_lo(vB.w); acc[7] += b2f_hi(vA.w) + b2f_hi(vB.w);
  }
  for (; i + 4 <= d; i += 4) {
    int s = esrc[o + i + g];
    uint4 v = ((const uint4*)(feat + (size_t)s * NF))[l];
    acc[0] += b2f_lo(v.x); acc[1] += b2f_hi(v.x);
    acc[2] += b2f_lo(v.y); acc[3] += b2f_hi(v.y);
    acc[4] += b2f_lo(v.z); acc[5] += b2f_hi(v.z);
    acc[6] += b2f_lo(v.w); acc[7] += b2f_hi(v.w);
  }
  if (i + g < d) {
    int s = esrc[o + i + g];
    uint4 v = ((const uint4*)(feat + (size_t)s * NF))[l];
    acc[0] += b2f_lo(v.x); acc[1] += b2f_hi(v.x);
    acc[2] += b2f_lo(v.y); acc[3] += b2f_hi(v.y);
    acc[4] += b2f_lo(v.z); acc[5] += b2f_hi(v.z);
    acc[6] += b2f_lo(v.w); acc[7] += b2f_hi(v.w);
  }
#pragma unroll
  for (int k = 0; k < 8; ++k) {
    acc[k] += __shfl_xor(acc[k], 16);
    acc[k] += __shfl_xor(acc[k], 32);
  }
  if (g == 0) {
    float inv = 1.0f / fmaxf((float)d, 1.0f);
    uint4 ov;
    ov.x = (uint)f2b(acc[0] * inv) | ((uint)f2b(acc[1] * inv) << 16);
    ov.y = (uint)f2b(acc[2] * inv) | ((uint)f2b(acc[3] * inv) << 16);
    ov.z = (uint)f2b(acc[4] * inv) | ((uint)f2b(acc[5] * inv) << 16);
    ov.w = (uint)f2b(acc[6] * inv) | ((uint)f2b(acc[7] * inv) << 16);
    ((uint4*)(aggm + (size_t)w * NF))[l] = ov;
  }
}

// ---------------- gather 2 (bf16 in, fp32 out, 64-dim rows) -----------------
__global__ __launch_bounds__(256) void gather2_kernel(
    const ushort* __restrict__ z, const int* __restrict__ esrc,
    const int* __restrict__ off, const int* __restrict__ deg,
    float* __restrict__ aggz, int nN) {
  const int w = (blockIdx.x * blockDim.x + threadIdx.x) >> 6;
  const int lane = threadIdx.x & 63;
  if (w >= nN) return;
  const int o = off[w];
  const int d = deg[w];
  const int g = lane >> 4;
  const int l = lane & 15;
  float acc[4] = {0.f, 0.f, 0.f, 0.f};
  int i = 0;
  for (; i + 8 <= d; i += 8) {
    int sA = esrc[o + i + g];
    int sB = esrc[o + i + 4 + g];
    uint2 vA = ((const uint2*)(z + (size_t)sA * NC))[l];
    uint2 vB = ((const uint2*)(z + (size_t)sB * NC))[l];
    acc[0] += b2f_lo(vA.x) + b2f_lo(vB.x); acc[1] += b2f_hi(vA.x) + b2f_hi(vB.x);
    acc[2] += b2f_lo(vA.y) + b2f_lo(vB.y); acc[3] += b2f_hi(vA.y) + b2f_hi(vB.y);
  }
  for (; i + 4 <= d; i += 4) {
    int s = esrc[o + i + g];
    uint2 v = ((const uint2*)(z + (size_t)s * NC))[l];
    acc[0] += b2f_lo(v.x); acc[1] += b2f_hi(v.x);
    acc[2] += b2f_lo(v.y); acc[3] += b2f_hi(v.y);
  }
  if (i + g < d) {
    int s = esrc[o + i + g];
    uint2 v = ((const uint2*)(z + (size_t)s * NC))[l];
    acc[0] += b2f_lo(v.x); acc[1] += b2f_hi(v.x);
    acc[2] += b2f_lo(v.y); acc[3] += b2f_hi(v.y);
  }
#pragma unroll
  for (int k = 0; k < 4; ++k) {
    acc[k] += __shfl_xor(acc[k], 16);
    acc[k] += __shfl_xor(acc[k], 32);
  }
  if (g == 0) {
    float inv = 1.0f / fmaxf((float)d, 1.0f);
    ((float4*)(aggz + (size_t)w * NC))[l] =
        make_float4(acc[0] * inv, acc[1] * inv, acc[2] * inv, acc[3] * inv);
  }
}

// ---------------- layer 1 (MFMA): h = relu([mean||x] @ Wcat + b) ------------
__global__ __launch_bounds__(256) void layer1_mfma(
    const ushort* __restrict__ xb, const ushort* __restrict__ aggb,
    const ushort* __restrict__ Wp, const float* __restrict__ b1,
    ushort* __restrict__ hb, int nN) {
  const int t = threadIdx.x;
  const int wv = t >> 6;
  const int lane = t & 63;
  const int base = blockIdx.x * 64;
  __shared__ ushort As[64][264];  // 256 cols + 8 pad
  for (int i = t; i < 64 * 32; i += 256) {
    int r = i >> 5, cq = i & 31;
    int node = base + r;
    short8 v = {};
    if (node < nN) {
      const ushort* sp = (cq < 16) ? (aggb + (size_t)node * NF + cq * 8)
                                   : (xb + (size_t)node * NF + (cq - 16) * 8);
      v = *(const short8*)sp;
    }
    *(short8*)&As[r][cq * 8] = v;
  }
  __syncthreads();

  f32x4 acc[8] = {};
  const int arow = wv * 16 + (lane & 15);
  const int kq = (lane >> 4) * 8;
#pragma unroll
  for (int kt = 0; kt < 8; ++kt) {
    short8 af = *(const short8*)&As[arow][kt * 32 + kq];
#pragma unroll
    for (int nt = 0; nt < 8; ++nt) {
      short8 bf = *(const short8*)(Wp + ((size_t)(kt * 8 + nt) * 64 + lane) * 8);
      acc[nt] = __builtin_amdgcn_mfma_f32_16x16x32_bf16(af, bf, acc[nt], 0, 0, 0);
    }
  }
  const int quad = lane >> 4;
  const int cl = lane & 15;
#pragma unroll
  for (int nt = 0; nt < 8; ++nt) {
    float bj = b1[nt * 16 + cl];
#pragma unroll
    for (int r = 0; r < 4; ++r) {
      int node = base + wv * 16 + quad * 4 + r;
      if (node < nN) {
        float vv = fmaxf(acc[nt][r] + bj, 0.0f);
        hb[(size_t)node * NF + nt * 16 + cl] = f2b(vv);
      }
    }
  }
}

// ---------------- layer 2a (MFMA): z = h @ W2l^T (bf16 out, no bias) --------
__global__ __launch_bounds__(256) void layer2a_mfma(
    const ushort* __restrict__ hb, const ushort* __restrict__ Wp,
    ushort* __restrict__ z, int nN) {
  const int t = threadIdx.x;
  const int wv = t >> 6;
  const int lane = t & 63;
  const int base = blockIdx.x * 64;
  __shared__ ushort As[64][136];  // 128 cols + 8 pad
  for (int i = t; i < 64 * 16; i += 256) {
    int r = i >> 4, cq = i & 15;
    int node = base + r;
    short8 v = {};
    if (node < nN) v = *(const short8*)(hb + (size_t)node * NF + cq * 8);
    *(short8*)&As[r][cq * 8] = v;
  }
  __syncthreads();

  f32x4 acc[4] = {};
  const int arow = wv * 16 + (lane & 15);
  const int kq = (lane >> 4) * 8;
#pragma unroll
  for (int kt = 0; kt < 4; ++kt) {
    short8 af = *(const short8*)&As[arow][kt * 32 + kq];
#pragma unroll
    for (int nt = 0; nt < 4; ++nt) {
      short8 bf = *(const short8*)(Wp + ((size_t)(kt * 4 + nt) * 64 + lane) * 8);
      acc[nt] = __builtin_amdgcn_mfma_f32_16x16x32_bf16(af, bf, acc[nt], 0, 0, 0);
    }
  }
  const int quad = lane >> 4;
  const int cl = lane & 15;
#pragma unroll
  for (int nt = 0; nt < 4; ++nt) {
#pragma unroll
    for (int r = 0; r < 4; ++r) {
      int node = base + wv * 16 + quad * 4 + r;
      if (node < nN) z[(size_t)node * NC + nt * 16 + cl] = f2b(acc[nt][r]);
    }
  }
}

// ---------------- layer 2b (MFMA): out = logsoftmax(aggz + h@W2r^T + b) -----
__global__ __launch_bounds__(256) void layer2b_mfma(
    const ushort* __restrict__ hb, const float* __restrict__ aggz,
    const ushort* __restrict__ Wp, const float* __restrict__ b2,
    float* __restrict__ out, int nN) {
  const int t = threadIdx.x;
  const int wv = t >> 6;
  const int lane = t & 63;
  const int base = blockIdx.x * 64;
  __shared__ ushort As[64][136];
  for (int i = t; i < 64 * 16; i += 256) {
    int r = i >> 4, cq = i & 15;
    int node = base + r;
    short8 v = {};
    if (node < nN) v = *(const short8*)(hb + (size_t)node * NF + cq * 8);
    *(short8*)&As[r][cq * 8] = v;
  }
  __syncthreads();

  f32x4 acc[4] = {};
  const int arow = wv * 16 + (lane & 15);
  const int kq = (lane >> 4) * 8;
#pragma unroll
  for (int kt = 0; kt < 4; ++kt) {
    short8 af = *(const short8*)&As[arow][kt * 32 + kq];
#pragma unroll
    for (int nt = 0; nt < 4; ++nt) {
      short8 bf = *(const short8*)(Wp + ((size_t)(kt * 4 + nt) * 64 + lane) * 8);
      acc[nt] = __builtin_amdgcn_mfma_f32_16x16x32_bf16(af, bf, acc[nt], 0, 0, 0);
    }
  }
  const int quad = lane >> 4;
  const int cl = lane & 15;
  float bj[4];
#pragma unroll
  for (int nt = 0; nt < 4; ++nt) bj[nt] = b2[nt * 16 + cl];

#pragma unroll
  for (int r = 0; r < 4; ++r) {
    int node = base + wv * 16 + quad * 4 + r;
    int nvalid = (node < nN);
    const float* ap = aggz + (size_t)node * NC;
    float v0 = acc[0][r] + bj[0] + (nvalid ? ap[0 * 16 + cl] : 0.0f);
    float v1 = acc[1][r] + bj[1] + (nvalid ? ap[1 * 16 + cl] : 0.0f);
    float v2 = acc[2][r] + bj[2] + (nvalid ? ap[2 * 16 + cl] : 0.0f);
    float v3 = acc[3][r] + bj[3] + (nvalid ? ap[3 * 16 + cl] : 0.0f);
    float mx = fmaxf(fmaxf(v0, v1), fmaxf(v2, v3));
#pragma unroll
    for (int s = 1; s < 16; s <<= 1) mx = fmaxf(mx, __shfl_xor(mx, s));
    float sm = expf(v0 - mx) + expf(v1 - mx) + expf(v2 - mx) + expf(v3 - mx);
#pragma unroll
    for (int s = 1; s < 16; s <<= 1) sm += __shfl_xor(sm, s);
    float ls = mx + logf(sm);
    if (nvalid) {
      float* op = out + (size_t)node * NC;
      op[0 * 16 + cl] = v0 - ls;
      op[1 * 16 + cl] = v1 - ls;
      op[2 * 16 + cl] = v2 - ls;
      op[3 * 16 + cl] = v3 - ls;
    }
  }
}

extern "C" void kernel_launch(void* const* d_in, const int* in_sizes, int n_in,
                              void* d_out, int out_size, void* d_ws, size_t ws_size,
                              hipStream_t stream) {
  const float* x   = (const float*)d_in[0];
  const int*   ei  = (const int*)d_in[1];
  const float* W1l = (const float*)d_in[2];
  const float* b1l = (const float*)d_in[3];
  const float* W1r = (const float*)d_in[4];
  const float* W2l = (const float*)d_in[5];
  const float* b2l = (const float*)d_in[6];
  const float* W2r = (const float*)d_in[7];
  float* out = (float*)d_out;

  const int nN = in_sizes[0] / NF;  // 100000
  const int nE = in_sizes[1] / 2;   // 1600000
  const int* src = ei;
  const int* dst = ei + nE;

  char* p = (char*)d_ws;
  ushort* xb   = (ushort*)p; p += (size_t)nN * NF * 2;   // reused as z after layer1
  ushort* hb   = (ushort*)p; p += (size_t)nN * NF * 2;
  ushort* aggb = (ushort*)p; p += (size_t)nN * NF * 2;   // reused as aggz (fp32, same bytes)
  ushort* Wp1  = (ushort*)p; p += 256 * 128 * 2;
  ushort* Wp2l = (ushort*)p; p += 128 * 64 * 2;
  ushort* Wp2r = (ushort*)p; p += 128 * 64 * 2;
  int* cntA = (int*)p; p += (size_t)NBKT * NBA * 4;
  int* cntS = (int*)p; p += (size_t)NBKT * NBA * 4;
  int* bsum = (int*)p; p += 512;
  int* deg  = (int*)p; p += (size_t)nN * 4;
  int* off  = (int*)p; p += (size_t)nN * 4;
  int* esrc = (int*)p; p += (size_t)nE * 4;
  int2* tmp = (int2*)p; p += (size_t)nE * 8;

  ushort* z    = xb;            // alias: xb dead after layer1
  float*  aggz = (float*)aggb;  // alias: aggb dead after layer1

  const int n4 = nN * NF / 4;
  const int nb_cast = (n4 + 255) / 256;
  const int epb = (nE + NBA - 1) / NBA;          // edges per pass-A block
  const int L = NBKT * NBA;                      // 125440 scan length
  const int nbL = (L + 1023) / 1024;             // 123 <= 128

  prep_kernel<<<nb_cast + 128 + 64, 256, 0, stream>>>(x, xb, n4, nb_cast,
                                                      W1l, W1r, Wp1,
                                                      W2l, W2r, Wp2l, Wp2r);

  // --- CSR build: atomic-free (LDS-only ranks) two-pass bucket sort ---
  bhistA_kernel<<<NBA, 256, 0, stream>>>(dst, cntA, nE, epb);
  scanL1_kernel<<<nbL, 256, 0, stream>>>(cntA, cntS, bsum, L);
  scanL2_kernel<<<1, 64, 0, stream>>>(bsum, nbL);
  scanL3_kernel<<<(L + 255) / 256, 256, 0, stream>>>(cntS, bsum, L);
  bscatA_kernel<<<NBA, 256, 0, stream>>>(src, dst, cntS, tmp, nE, epb);
  bsortB_kernel<<<NBKT, 256, 0, stream>>>(tmp, cntS, esrc, deg, off, nN, nE);

  // --- layer 1 ---
  gather1_kernel<<<(nN + 3) / 4, 256, 0, stream>>>(xb, esrc, off, deg, aggb, nN);
  layer1_mfma<<<(nN + 63) / 64, 256, 0, stream>>>(xb, aggb, Wp1, b1l, hb, nN);

  // --- layer 2 (projection-first: z = h@W2l, then mean, then +h@W2r) ---
  layer2a_mfma<<<(nN + 63) / 64, 256, 0, stream>>>(hb, Wp2l, z, nN);
  gather2_kernel<<<(nN + 3) / 4, 256, 0, stream>>>(z, esrc, off, deg, aggz, nN);
  layer2b_mfma<<<(nN + 63) / 64, 256, 0, stream>>>(hb, aggz, Wp2r, b2l, out, nN);
}

// Round 9
// 315.699 us; speedup vs baseline: 18.4382x; 1.0687x over previous
//
#include <hip/hip_runtime.h>

#define NF 128   // FEATURE == HIDDEN
#define NC 64    // CLASSES
#define NBA 640  // pass-A blocks
#define NBKT 196 // ceil(100000/512) coarse buckets

typedef short short8 __attribute__((ext_vector_type(8)));
typedef unsigned short ushort;
typedef float f32x4 __attribute__((ext_vector_type(4)));
typedef float f32x2 __attribute__((ext_vector_type(2)));
typedef unsigned int uint;
typedef unsigned char uchar;

__device__ __forceinline__ ushort f2b(float x) {  // RNE float->bf16
  unsigned u = __builtin_bit_cast(unsigned, x);
  u += 0x7fffu + ((u >> 16) & 1u);
  return (ushort)(u >> 16);
}

// ---------------- fused prep: cast x->bf16 + fp8, pack W1, pack W2l/W2r -----
__global__ void prep_kernel(const float* __restrict__ x, ushort* __restrict__ xb,
                            uchar* __restrict__ x8, int n4, int nb_cast,
                            const float* __restrict__ W1l, const float* __restrict__ W1r,
                            ushort* __restrict__ Wp1,
                            const float* __restrict__ W2l, const float* __restrict__ W2r,
                            ushort* __restrict__ Wp2l, ushort* __restrict__ Wp2r) {
  int b = blockIdx.x;
  if (b < nb_cast) {
    int i = b * 256 + threadIdx.x;
    if (i >= n4) return;
    float4 v = ((const float4*)x)[i];
    ushort4 o;
    o.x = f2b(v.x); o.y = f2b(v.y); o.z = f2b(v.z); o.w = f2b(v.w);
    ((ushort4*)xb)[i] = o;
    int u = __builtin_amdgcn_cvt_pk_fp8_f32(v.x, v.y, 0, false);
    u = __builtin_amdgcn_cvt_pk_fp8_f32(v.z, v.w, u, true);
    ((uint*)x8)[i] = (uint)u;
  } else if (b < nb_cast + 128) {
    int tid = (b - nb_cast) * 256 + threadIdx.x;  // 0..32767
    int j = tid & 7;
    int lane = (tid >> 3) & 63;
    int tile = tid >> 9;
    int nt = tile & 7, kt = tile >> 3;
    int k = kt * 32 + ((lane >> 4) << 3) + j;
    int n = nt * 16 + (lane & 15);
    float v = (k < 128) ? W1l[n * 128 + k] : W1r[n * 128 + (k - 128)];
    Wp1[tid] = f2b(v);
  } else {
    int tid0 = (b - nb_cast - 128) * 256 + threadIdx.x;  // 0..16383
    int which = tid0 >> 13;
    int tid = tid0 & 8191;
    int j = tid & 7;
    int lane = (tid >> 3) & 63;
    int tile = tid >> 9;
    int nt = tile & 3, kt = tile >> 2;
    int k = kt * 32 + ((lane >> 4) << 3) + j;
    int n = nt * 16 + (lane & 15);
    const float* W = which ? W2r : W2l;
    ushort* Wp = which ? Wp2r : Wp2l;
    Wp[tid] = f2b(W[n * 128 + k]);
  }
}

// ---------------- CSR build pass A1: per-block coarse histogram -------------
__global__ __launch_bounds__(256) void bhistA_kernel(const int* __restrict__ dst,
                                                     int* __restrict__ cntA,
                                                     int nE, int epb) {
  __shared__ int lh[NBKT];
  const int t = threadIdx.x;
  for (int i = t; i < NBKT; i += 256) lh[i] = 0;
  __syncthreads();
  int s0 = blockIdx.x * epb, s1 = min(nE, s0 + epb);
  for (int e = s0 + t; e < s1; e += 256) atomicAdd(&lh[dst[e] >> 9], 1);
  __syncthreads();
  for (int i = t; i < NBKT; i += 256)
    cntA[(size_t)i * NBA + blockIdx.x] = lh[i];
}

// ---------------- generic exclusive scan (3 kernels) over L <= 131072 -------
__global__ __launch_bounds__(256) void scanL1_kernel(const int* __restrict__ in,
                                                     int* __restrict__ out,
                                                     int* __restrict__ bsum, int L) {
  const int t = threadIdx.x;
  const int base = blockIdx.x * 1024 + t * 4;
  int v[4];
  int tsum = 0;
#pragma unroll
  for (int k = 0; k < 4; ++k) {
    v[k] = (base + k < L) ? in[base + k] : 0;
    tsum += v[k];
  }
  int lane = t & 63, wid = t >> 6;
  int x = tsum;
#pragma unroll
  for (int d = 1; d < 64; d <<= 1) {
    int y = __shfl_up(x, d);
    if (lane >= d) x += y;
  }
  __shared__ int wsum[4];
  if (lane == 63) wsum[wid] = x;
  __syncthreads();
  int wbase = 0;
  for (int w = 0; w < wid; ++w) wbase += wsum[w];
  int run = wbase + x - tsum;
#pragma unroll
  for (int k = 0; k < 4; ++k) {
    if (base + k < L) out[base + k] = run;
    run += v[k];
  }
  if (t == 0) bsum[blockIdx.x] = wsum[0] + wsum[1] + wsum[2] + wsum[3];
}

__global__ void scanL2_kernel(int* __restrict__ bsum, int nb) {
  int lane = threadIdx.x;
  int i0 = 2 * lane, i1 = 2 * lane + 1;
  int v0 = (i0 < nb) ? bsum[i0] : 0;
  int v1 = (i1 < nb) ? bsum[i1] : 0;
  int s = v0 + v1;
  int x = s;
#pragma unroll
  for (int d = 1; d < 64; d <<= 1) {
    int y = __shfl_up(x, d);
    if (lane >= d) x += y;
  }
  int ex = x - s;
  if (i0 < nb) bsum[i0] = ex;
  if (i1 < nb) bsum[i1] = ex + v0;
}

__global__ void scanL3_kernel(int* __restrict__ out, const int* __restrict__ bsum, int L) {
  int i = blockIdx.x * blockDim.x + threadIdx.x;
  if (i < L) out[i] += bsum[i >> 10];
}

// ---------------- CSR build pass A3: scatter into coarse buckets ------------
// tmp entry: (dst & 511) << 17 | src   (26 bits)
__global__ __launch_bounds__(256) void bscatA_kernel(const int* __restrict__ src,
                                                     const int* __restrict__ dst,
                                                     const int* __restrict__ cntS,
                                                     uint* __restrict__ tmp,
                                                     int nE, int epb) {
  __shared__ int base[NBKT];
  __shared__ int cur[NBKT];
  const int t = threadIdx.x;
  for (int i = t; i < NBKT; i += 256) {
    base[i] = cntS[(size_t)i * NBA + blockIdx.x];
    cur[i] = 0;
  }
  __syncthreads();
  int s0 = blockIdx.x * epb, s1 = min(nE, s0 + epb);
  for (int e = s0 + t; e < s1; e += 256) {
    int d = dst[e];
    int s = src[e];
    int b = d >> 9;
    int r = atomicAdd(&cur[b], 1);
    tmp[base[b] + r] = ((uint)(d & 511) << 17) | (uint)s;
  }
}

// ---------------- CSR build pass B: per-bucket node sort + deg/off ----------
__global__ __launch_bounds__(256) void bsortB_kernel(const uint* __restrict__ tmp,
                                                     const int* __restrict__ cntS,
                                                     int* __restrict__ esrc,
                                                     int* __restrict__ deg,
                                                     int* __restrict__ off,
                                                     int nN, int nE) {
  const int bkt = blockIdx.x;
  const int t = threadIdx.x;
  __shared__ int lh[512];
  __shared__ int cur[512];
  __shared__ int wsum[4];
  const int start = cntS[(size_t)bkt * NBA];
  const int end = (bkt + 1 < NBKT) ? cntS[(size_t)(bkt + 1) * NBA] : nE;
  lh[t] = 0;
  lh[t + 256] = 0;
  __syncthreads();
  for (int i = start + t; i < end; i += 256) {
    uint e = tmp[i];
    atomicAdd(&lh[e >> 17], 1);
  }
  __syncthreads();
  int v0 = lh[2 * t], v1 = lh[2 * t + 1];
  int ts = v0 + v1;
  int lane = t & 63, wid = t >> 6;
  int x = ts;
#pragma unroll
  for (int d = 1; d < 64; d <<= 1) {
    int y = __shfl_up(x, d);
    if (lane >= d) x += y;
  }
  if (lane == 63) wsum[wid] = x;
  __syncthreads();
  int wb = 0;
  for (int w = 0; w < wid; ++w) wb += wsum[w];
  int ex = wb + x - ts;
  cur[2 * t] = ex;
  cur[2 * t + 1] = ex + v0;
  int n0 = (bkt << 9) + 2 * t, n1 = n0 + 1;
  if (n0 < nN) { off[n0] = start + ex;      deg[n0] = v0; }
  if (n1 < nN) { off[n1] = start + ex + v0; deg[n1] = v1; }
  __syncthreads();
  for (int i = start + t; i < end; i += 256) {
    uint e = tmp[i];
    int r = atomicAdd(&cur[e >> 17], 1);
    esrc[start + r] = (int)(e & 0x1FFFFu);
  }
}

// ---------------- gather 1 (fp8 in, bf16 out, 128-dim rows) -----------------
// one wave per node; 8 edges in flight (4 lane-groups x 2 unroll), 8B/lane.
__global__ __launch_bounds__(256) void gather1_kernel(
    const uchar* __restrict__ x8, const int* __restrict__ esrc,
    const int* __restrict__ off, const int* __restrict__ deg,
    ushort* __restrict__ aggm, int nN) {
  const int w = (blockIdx.x * blockDim.x + threadIdx.x) >> 6;
  const int lane = threadIdx.x & 63;
  if (w >= nN) return;
  const int o = off[w];
  const int d = deg[w];
  const int g = lane >> 4;
  const int l = lane & 15;
  f32x2 acc[4] = {};
  int i = 0;
  for (; i + 8 <= d; i += 8) {
    int sA = esrc[o + i + g];
    int sB = esrc[o + i + 4 + g];
    uint2 vA = ((const uint2*)(x8 + (size_t)sA * NF))[l];
    uint2 vB = ((const uint2*)(x8 + (size_t)sB * NF))[l];
    acc[0] += __builtin_amdgcn_cvt_pk_f32_fp8(vA.x, false) +
              __builtin_amdgcn_cvt_pk_f32_fp8(vB.x, false);
    acc[1] += __builtin_amdgcn_cvt_pk_f32_fp8(vA.x, true) +
              __builtin_amdgcn_cvt_pk_f32_fp8(vB.x, true);
    acc[2] += __builtin_amdgcn_cvt_pk_f32_fp8(vA.y, false) +
              __builtin_amdgcn_cvt_pk_f32_fp8(vB.y, false);
    acc[3] += __builtin_amdgcn_cvt_pk_f32_fp8(vA.y, true) +
              __builtin_amdgcn_cvt_pk_f32_fp8(vB.y, true);
  }
  for (; i + 4 <= d; i += 4) {
    int s = esrc[o + i + g];
    uint2 v = ((const uint2*)(x8 + (size_t)s * NF))[l];
    acc[0] += __builtin_amdgcn_cvt_pk_f32_fp8(v.x, false);
    acc[1] += __builtin_amdgcn_cvt_pk_f32_fp8(v.x, true);
    acc[2] += __builtin_amdgcn_cvt_pk_f32_fp8(v.y, false);
    acc[3] += __builtin_amdgcn_cvt_pk_f32_fp8(v.y, true);
  }
  if (i + g < d) {
    int s = esrc[o + i + g];
    uint2 v = ((const uint2*)(x8 + (size_t)s * NF))[l];
    acc[0] += __builtin_amdgcn_cvt_pk_f32_fp8(v.x, false);
    acc[1] += __builtin_amdgcn_cvt_pk_f32_fp8(v.x, true);
    acc[2] += __builtin_amdgcn_cvt_pk_f32_fp8(v.y, false);
    acc[3] += __builtin_amdgcn_cvt_pk_f32_fp8(v.y, true);
  }
  float r[8];
#pragma unroll
  for (int k = 0; k < 4; ++k) { r[2 * k] = acc[k].x; r[2 * k + 1] = acc[k].y; }
#pragma unroll
  for (int k = 0; k < 8; ++k) {
    r[k] += __shfl_xor(r[k], 16);
    r[k] += __shfl_xor(r[k], 32);
  }
  if (g == 0) {
    float inv = 1.0f / fmaxf((float)d, 1.0f);
    uint4 ov;
    ov.x = (uint)f2b(r[0] * inv) | ((uint)f2b(r[1] * inv) << 16);
    ov.y = (uint)f2b(r[2] * inv) | ((uint)f2b(r[3] * inv) << 16);
    ov.z = (uint)f2b(r[4] * inv) | ((uint)f2b(r[5] * inv) << 16);
    ov.w = (uint)f2b(r[6] * inv) | ((uint)f2b(r[7] * inv) << 16);
    ((uint4*)(aggm + (size_t)w * NF))[l] = ov;
  }
}

// ---------------- gather 2 (fp8 in, fp32 out, 64-dim rows, permuted) --------
// z8 row layout: byte (cl*4 + nt) holds logical col (nt*16 + cl).
// aggz keeps the same permuted layout; layer2b consumes it as float4 per cl.
__global__ __launch_bounds__(256) void gather2_kernel(
    const uchar* __restrict__ z8, const int* __restrict__ esrc,
    const int* __restrict__ off, const int* __restrict__ deg,
    float* __restrict__ aggz, int nN) {
  const int w = (blockIdx.x * blockDim.x + threadIdx.x) >> 6;
  const int lane = threadIdx.x & 63;
  if (w >= nN) return;
  const int o = off[w];
  const int d = deg[w];
  const int g = lane >> 4;
  const int l = lane & 15;
  f32x2 acc[2] = {};
  int i = 0;
  for (; i + 8 <= d; i += 8) {
    int sA = esrc[o + i + g];
    int sB = esrc[o + i + 4 + g];
    uint vA = ((const uint*)(z8 + (size_t)sA * NC))[l];
    uint vB = ((const uint*)(z8 + (size_t)sB * NC))[l];
    acc[0] += __builtin_amdgcn_cvt_pk_f32_fp8(vA, false) +
              __builtin_amdgcn_cvt_pk_f32_fp8(vB, false);
    acc[1] += __builtin_amdgcn_cvt_pk_f32_fp8(vA, true) +
              __builtin_amdgcn_cvt_pk_f32_fp8(vB, true);
  }
  for (; i + 4 <= d; i += 4) {
    int s = esrc[o + i + g];
    uint v = ((const uint*)(z8 + (size_t)s * NC))[l];
    acc[0] += __builtin_amdgcn_cvt_pk_f32_fp8(v, false);
    acc[1] += __builtin_amdgcn_cvt_pk_f32_fp8(v, true);
  }
  if (i + g < d) {
    int s = esrc[o + i + g];
    uint v = ((const uint*)(z8 + (size_t)s * NC))[l];
    acc[0] += __builtin_amdgcn_cvt_pk_f32_fp8(v, false);
    acc[1] += __builtin_amdgcn_cvt_pk_f32_fp8(v, true);
  }
  float r[4] = {acc[0].x, acc[0].y, acc[1].x, acc[1].y};
#pragma unroll
  for (int k = 0; k < 4; ++k) {
    r[k] += __shfl_xor(r[k], 16);
    r[k] += __shfl_xor(r[k], 32);
  }
  if (g == 0) {
    float inv = 1.0f / fmaxf((float)d, 1.0f);
    ((float4*)(aggz + (size_t)w * NC))[l] =
        make_float4(r[0] * inv, r[1] * inv, r[2] * inv, r[3] * inv);
  }
}

// ---------------- layer 1 (MFMA): h = relu([mean||x] @ Wcat + b) ------------
__global__ __launch_bounds__(256) void layer1_mfma(
    const ushort* __restrict__ xb, const ushort* __restrict__ aggb,
    const ushort* __restrict__ Wp, const float* __restrict__ b1,
    ushort* __restrict__ hb, int nN) {
  const int t = threadIdx.x;
  const int wv = t >> 6;
  const int lane = t & 63;
  const int base = blockIdx.x * 64;
  __shared__ ushort As[64][264];  // 256 cols + 8 pad
  for (int i = t; i < 64 * 32; i += 256) {
    int r = i >> 5, cq = i & 31;
    int node = base + r;
    short8 v = {};
    if (node < nN) {
      const ushort* sp = (cq < 16) ? (aggb + (size_t)node * NF + cq * 8)
                                   : (xb + (size_t)node * NF + (cq - 16) * 8);
      v = *(const short8*)sp;
    }
    *(short8*)&As[r][cq * 8] = v;
  }
  __syncthreads();

  f32x4 acc[8] = {};
  const int arow = wv * 16 + (lane & 15);
  const int kq = (lane >> 4) * 8;
#pragma unroll
  for (int kt = 0; kt < 8; ++kt) {
    short8 af = *(const short8*)&As[arow][kt * 32 + kq];
#pragma unroll
    for (int nt = 0; nt < 8; ++nt) {
      short8 bf = *(const short8*)(Wp + ((size_t)(kt * 8 + nt) * 64 + lane) * 8);
      acc[nt] = __builtin_amdgcn_mfma_f32_16x16x32_bf16(af, bf, acc[nt], 0, 0, 0);
    }
  }
  const int quad = lane >> 4;
  const int cl = lane & 15;
#pragma unroll
  for (int nt = 0; nt < 8; ++nt) {
    float bj = b1[nt * 16 + cl];
#pragma unroll
    for (int r = 0; r < 4; ++r) {
      int node = base + wv * 16 + quad * 4 + r;
      if (node < nN) {
        float vv = fmaxf(acc[nt][r] + bj, 0.0f);
        hb[(size_t)node * NF + nt * 16 + cl] = f2b(vv);
      }
    }
  }
}

// ---------------- layer 2a (MFMA): z = h @ W2l^T -> fp8, permuted layout ----
__global__ __launch_bounds__(256) void layer2a_mfma(
    const ushort* __restrict__ hb, const ushort* __restrict__ Wp,
    uchar* __restrict__ z8, int nN) {
  const int t = threadIdx.x;
  const int wv = t >> 6;
  const int lane = t & 63;
  const int base = blockIdx.x * 64;
  __shared__ ushort As[64][136];  // 128 cols + 8 pad
  for (int i = t; i < 64 * 16; i += 256) {
    int r = i >> 4, cq = i & 15;
    int node = base + r;
    short8 v = {};
    if (node < nN) v = *(const short8*)(hb + (size_t)node * NF + cq * 8);
    *(short8*)&As[r][cq * 8] = v;
  }
  __syncthreads();

  f32x4 acc[4] = {};
  const int arow = wv * 16 + (lane & 15);
  const int kq = (lane >> 4) * 8;
#pragma unroll
  for (int kt = 0; kt < 4; ++kt) {
    short8 af = *(const short8*)&As[arow][kt * 32 + kq];
#pragma unroll
    for (int nt = 0; nt < 4; ++nt) {
      short8 bf = *(const short8*)(Wp + ((size_t)(kt * 4 + nt) * 64 + lane) * 8);
      acc[nt] = __builtin_amdgcn_mfma_f32_16x16x32_bf16(af, bf, acc[nt], 0, 0, 0);
    }
  }
  const int quad = lane >> 4;
  const int cl = lane & 15;
#pragma unroll
  for (int r = 0; r < 4; ++r) {
    int node = base + wv * 16 + quad * 4 + r;
    if (node < nN) {
      int u = __builtin_amdgcn_cvt_pk_fp8_f32(acc[0][r], acc[1][r], 0, false);
      u = __builtin_amdgcn_cvt_pk_fp8_f32(acc[2][r], acc[3][r], u, true);
      ((uint*)(z8 + (size_t)node * NC))[cl] = (uint)u;
    }
  }
}

// ---------------- layer 2b (MFMA): out = logsoftmax(aggz + h@W2r^T + b) -----
__global__ __launch_bounds__(256) void layer2b_mfma(
    const ushort* __restrict__ hb, const float* __restrict__ aggz,
    const ushort* __restrict__ Wp, const float* __restrict__ b2,
    float* __restrict__ out, int nN) {
  const int t = threadIdx.x;
  const int wv = t >> 6;
  const int lane = t & 63;
  const int base = blockIdx.x * 64;
  __shared__ ushort As[64][136];
  for (int i = t; i < 64 * 16; i += 256) {
    int r = i >> 4, cq = i & 15;
    int node = base + r;
    short8 v = {};
    if (node < nN) v = *(const short8*)(hb + (size_t)node * NF + cq * 8);
    *(short8*)&As[r][cq * 8] = v;
  }
  __syncthreads();

  f32x4 acc[4] = {};
  const int arow = wv * 16 + (lane & 15);
  const int kq = (lane >> 4) * 8;
#pragma unroll
  for (int kt = 0; kt < 4; ++kt) {
    short8 af = *(const short8*)&As[arow][kt * 32 + kq];
#pragma unroll
    for (int nt = 0; nt < 4; ++nt) {
      short8 bf = *(const short8*)(Wp + ((size_t)(kt * 4 + nt) * 64 + lane) * 8);
      acc[nt] = __builtin_amdgcn_mfma_f32_16x16x32_bf16(af, bf, acc[nt], 0, 0, 0);
    }
  }
  const int quad = lane >> 4;
  const int cl = lane & 15;
  float bj[4];
#pragma unroll
  for (int nt = 0; nt < 4; ++nt) bj[nt] = b2[nt * 16 + cl];

#pragma unroll
  for (int r = 0; r < 4; ++r) {
    int node = base + wv * 16 + quad * 4 + r;
    int nvalid = (node < nN);
    float a0 = 0.f, a1 = 0.f, a2 = 0.f, a3 = 0.f;
    if (nvalid) {
      // aggz is in the permuted layout: float4 at [cl] = cols {nt*16+cl}
      float4 av = ((const float4*)(aggz + (size_t)node * NC))[cl];
      a0 = av.x; a1 = av.y; a2 = av.z; a3 = av.w;
    }
    float v0 = acc[0][r] + bj[0] + a0;
    float v1 = acc[1][r] + bj[1] + a1;
    float v2 = acc[2][r] + bj[2] + a2;
    float v3 = acc[3][r] + bj[3] + a3;
    float mx = fmaxf(fmaxf(v0, v1), fmaxf(v2, v3));
#pragma unroll
    for (int s = 1; s < 16; s <<= 1) mx = fmaxf(mx, __shfl_xor(mx, s));
    float sm = expf(v0 - mx) + expf(v1 - mx) + expf(v2 - mx) + expf(v3 - mx);
#pragma unroll
    for (int s = 1; s < 16; s <<= 1) sm += __shfl_xor(sm, s);
    float ls = mx + logf(sm);
    if (nvalid) {
      float* op = out + (size_t)node * NC;
      op[0 * 16 + cl] = v0 - ls;
      op[1 * 16 + cl] = v1 - ls;
      op[2 * 16 + cl] = v2 - ls;
      op[3 * 16 + cl] = v3 - ls;
    }
  }
}

extern "C" void kernel_launch(void* const* d_in, const int* in_sizes, int n_in,
                              void* d_out, int out_size, void* d_ws, size_t ws_size,
                              hipStream_t stream) {
  const float* x   = (const float*)d_in[0];
  const int*   ei  = (const int*)d_in[1];
  const float* W1l = (const float*)d_in[2];
  const float* b1l = (const float*)d_in[3];
  const float* W1r = (const float*)d_in[4];
  const float* W2l = (const float*)d_in[5];
  const float* b2l = (const float*)d_in[6];
  const float* W2r = (const float*)d_in[7];
  float* out = (float*)d_out;

  const int nN = in_sizes[0] / NF;  // 100000
  const int nE = in_sizes[1] / 2;   // 1600000
  const int* src = ei;
  const int* dst = ei + nE;

  char* p = (char*)d_ws;
  ushort* xb   = (ushort*)p; p += (size_t)nN * NF * 2;
  ushort* hb   = (ushort*)p; p += (size_t)nN * NF * 2;   // first half doubles as x8
  ushort* aggb = (ushort*)p; p += (size_t)nN * NF * 2;   // reused as aggz (fp32, same bytes)
  ushort* Wp1  = (ushort*)p; p += 256 * 128 * 2;
  ushort* Wp2l = (ushort*)p; p += 128 * 64 * 2;
  ushort* Wp2r = (ushort*)p; p += 128 * 64 * 2;
  int* cntA = (int*)p; p += (size_t)NBKT * NBA * 4;
  int* cntS = (int*)p; p += (size_t)NBKT * NBA * 4;
  int* bsum = (int*)p; p += 512;
  int* deg  = (int*)p; p += (size_t)nN * 4;
  int* off  = (int*)p; p += (size_t)nN * 4;
  int* esrc = (int*)p; p += (size_t)nE * 4;
  uint* tmp = (uint*)p; p += (size_t)nE * 4;             // doubles as z8 after bsortB

  uchar* x8   = (uchar*)hb;     // alias: hb written only in layer1, after gather1
  uchar* z8   = (uchar*)tmp;    // alias: tmp dead after bsortB
  float* aggz = (float*)aggb;   // alias: aggb dead after layer1

  const int n4 = nN * NF / 4;
  const int nb_cast = (n4 + 255) / 256;
  const int epb = (nE + NBA - 1) / NBA;
  const int L = NBKT * NBA;
  const int nbL = (L + 1023) / 1024;

  prep_kernel<<<nb_cast + 128 + 64, 256, 0, stream>>>(x, xb, x8, n4, nb_cast,
                                                      W1l, W1r, Wp1,
                                                      W2l, W2r, Wp2l, Wp2r);

  // --- CSR build: atomic-free (LDS-only ranks) two-pass bucket sort ---
  bhistA_kernel<<<NBA, 256, 0, stream>>>(dst, cntA, nE, epb);
  scanL1_kernel<<<nbL, 256, 0, stream>>>(cntA, cntS, bsum, L);
  scanL2_kernel<<<1, 64, 0, stream>>>(bsum, nbL);
  scanL3_kernel<<<(L + 255) / 256, 256, 0, stream>>>(cntS, bsum, L);
  bscatA_kernel<<<NBA, 256, 0, stream>>>(src, dst, cntS, tmp, nE, epb);
  bsortB_kernel<<<NBKT, 256, 0, stream>>>(tmp, cntS, esrc, deg, off, nN, nE);

  // --- layer 1 ---
  gather1_kernel<<<(nN + 3) / 4, 256, 0, stream>>>(x8, esrc, off, deg, aggb, nN);
  layer1_mfma<<<(nN + 63) / 64, 256, 0, stream>>>(xb, aggb, Wp1, b1l, hb, nN);

  // --- layer 2 (projection-first: z = h@W2l -> fp8, mean, +h@W2r) ---
  layer2a_mfma<<<(nN + 63) / 64, 256, 0, stream>>>(hb, Wp2l, z8, nN);
  gather2_kernel<<<(nN + 3) / 4, 256, 0, stream>>>(z8, esrc, off, deg, aggz, nN);
  layer2b_mfma<<<(nN + 63) / 64, 256, 0, stream>>>(hb, aggz, Wp2r, b2l, out, nN);
}